// Round 16
// baseline (1044.789 us; speedup 1.0000x reference)
//
#include <hip/hip_runtime.h>
#include <hip/hip_bf16.h>
#include <math.h>

#define DEV __device__ __forceinline__

DEV float sigmoidf_(float x) { return 1.0f / (1.0f + __expf(-x)); }

// Broadcast lane `lane` (wave-uniform index) of v to all lanes via
// v_readlane_b32 (VALU, result in SGPR). Replaces wave-uniform
// ds_read_b128 broadcasts which saturated the single LDS pipe in R15
// (420 LDS ops/wave/iter x 12cyc x 128 waves/CU = 808us = the runtime).
DEV float RLf(float v, int lane) {
  return __int_as_float(__builtin_amdgcn_readlane(__float_as_int(v), lane));
}

#define LO(OP) OP(0) OP(1) OP(2) OP(3) OP(4)
#define L6(OP) OP(0) OP(1) OP(2) OP(3) OP(4) OP(5)

// Compact A staging (240 used entries of the 22x22 matrix)
#define AROB 0
#define AORB 16
#define AODB 32
#define ADOB 144
#define ANUM 256

DEV float gstep(float x, float h, const float* k, const float* rk, const float* bb) {
  const float z  = sigmoidf_(fmaf(x, k[0], bb[0]) + fmaf(h, rk[0], bb[3]));
  const float r  = sigmoidf_(fmaf(x, k[1], bb[1]) + fmaf(h, rk[1], bb[4]));
  const float hh = tanhf(fmaf(x, k[2], bb[2]) + r * fmaf(h, rk[2], bb[5]));
  return z * h + (1.f - z) * hh;
}

__global__ void __launch_bounds__(64, 1)
temporal_kernel(const float* __restrict__ T, const float* __restrict__ GK,
                const float* __restrict__ GRK, const float* __restrict__ GB,
                const float* __restrict__ WO, const int* __restrict__ IDX,
                float* __restrict__ tp) {
  const int i = threadIdx.x;
  __shared__ float fb[3][75];
  __shared__ float gg[3][75];
  if (i < 3) {
    float k0[3], k1[3], rk0[3], rk1[3];
#pragma unroll
    for (int q = 0; q < 3; ++q) {
      k0[q]  = GK[i * 6 + q];      k1[q]  = GK[i * 6 + 3 + q];
      rk0[q] = GRK[i * 6 + q];     rk1[q] = GRK[i * 6 + 3 + q];
    }
    const float* B0 = GB + i * 12;
    const float* B1 = GB + i * 12 + 6;
    float h = 0.f;
    for (int s = 0; s < 75; ++s) { h = gstep(T[i * 75 + s], h, k0, rk0, B0); fb[i][s] = h; }
    h = 0.f;
    for (int s = 0; s < 75; ++s) { h = gstep(fb[i][74 - s], h, k1, rk1, B1); gg[i][s] = h; }
    const float wo = WO[i];
    float mx = -1e30f;
    for (int s = 0; s < 75; ++s) mx = fmaxf(mx, gg[i][s] * wo);
    float sum = 0.f;
    for (int s = 0; s < 75; ++s) { const float e = __expf(gg[i][s] * wo - mx); fb[i][s] = e; sum += e; }
    const float inv = 1.f / sum;
    for (int j = 0; j < 60; ++j) tp[i * 60 + j] = fb[i][IDX[j]] * inv;
  }
}

// Weight repack (proven R13): lane c's 4 consecutive k-values as one dwordx4.
// ws layout (1KB/k4-block): ZR[0..31] RR[32..63] MR[64..95] ZO[96..143]
// RO[144..191] MO[192..239] ZD[240..271] RD[272..303] MD[304..335]
__global__ void __launch_bounds__(64, 1) prep_kernel(
    const float* __restrict__ WzR, const float* __restrict__ WrR, const float* __restrict__ WmR,
    const float* __restrict__ WzO, const float* __restrict__ WrO, const float* __restrict__ WmO,
    const float* __restrict__ WzD, const float* __restrict__ WrD, const float* __restrict__ WmD,
    char* __restrict__ ws) {
  const int fi = blockIdx.x;
  const int c = threadIdx.x;
  const float* W; int base;
  if      (fi <  32) { W = WzR; base = 0;   }
  else if (fi <  64) { W = WrR; base = 32;  }
  else if (fi <  96) { W = WmR; base = 64;  }
  else if (fi < 144) { W = WzO; base = 96;  }
  else if (fi < 192) { W = WrO; base = 144; }
  else if (fi < 240) { W = WmO; base = 192; }
  else if (fi < 272) { W = WzD; base = 240; }
  else if (fi < 304) { W = WrD; base = 272; }
  else               { W = WmD; base = 304; }
  const int kb = fi - base;
  float4 v;
  v.x = W[(kb * 4 + 0) * 64 + c];
  v.y = W[(kb * 4 + 1) * 64 + c];
  v.z = W[(kb * 4 + 2) * 64 + c];
  v.w = W[(kb * 4 + 3) * 64 + c];
  *(float4*)(ws + 1024 + (size_t)fi * 1024 + c * 16) = v;
}

// 256 threads = 4 waves on ONE batch element. Rows partitioned per wave
// (w0: O 0-4, w1: O 5-9, w2: D 0-5, w3: D 6-10 + R). Own h/n live in
// REGISTERS; matvec operands broadcast via v_readlane (VALU path). LDS
// used only for cross-wave h exchange (n-staging) - ~75 ops/wave/iter.
__global__ void __launch_bounds__(256) ggnn_main(
    const float* __restrict__ X, const float* __restrict__ A,
    const float* __restrict__ WgR, const float* __restrict__ bgR,
    const float* __restrict__ WgO, const float* __restrict__ bgO,
    const float* __restrict__ WgD, const float* __restrict__ bgD,
    const float* __restrict__ bmR, const float* __restrict__ bmO, const float* __restrict__ bmD,
    const float* __restrict__ W1R, const float* __restrict__ b1R, const float* __restrict__ W2R,
    const float* __restrict__ W1O, const float* __restrict__ b1O, const float* __restrict__ W2O,
    const float* __restrict__ W1D, const float* __restrict__ b1D, const float* __restrict__ W2D,
    const char* __restrict__ ws, const float* __restrict__ tp,
    float* __restrict__ out) {
  const int b = blockIdx.x;
  const int w = threadIdx.x >> 6;
  const int c = threadIdx.x & 63;
  const int tid = threadIdx.x;

  __shared__ __align__(16) float xS[896];      // X stage
  __shared__ __align__(16) float hS[22 * 64];  // h rows: 0=R, 1-10=O, 11-21=D
  __shared__ float sA2[ANUM];
  __shared__ float red[16];

  const float4* pk = (const float4*)(ws + 1024);
  const float4* pWzR = pk + 0   * 64;
  const float4* pWrR = pk + 32  * 64;
  const float4* pWmR = pk + 64  * 64;
  const float4* pWzO = pk + 96  * 64;
  const float4* pWrO = pk + 144 * 64;
  const float4* pWmO = pk + 192 * 64;
  const float4* pWzD = pk + 240 * 64;
  const float4* pWrD = pk + 272 * 64;
  const float4* pWmD = pk + 304 * 64;

  const float* Xb = X + (size_t)b * 880;
  const float* Ab = A + (size_t)b * 484;
  for (int t = tid; t < 880; t += 256) xS[t] = Xb[t];
  if (tid < 10) {
    sA2[AROB + tid] = Ab[1 + tid];
    sA2[AORB + tid] = Ab[(1 + tid) * 22];
  }
  for (int t = tid; t < 110; t += 256) {
    const int i = t / 11, j = t - i * 11;
    sA2[AODB + t] = Ab[(1 + i) * 22 + 11 + j];
  }
  for (int t = tid; t < 110; t += 256) {
    const int i = t / 10, j = t - i * 10;
    sA2[ADOB + t] = Ab[(11 + i) * 22 + 1 + j];
  }
  __syncthreads();

  float h0, h1, h2, h3, h4, h5;   // own rows (meaning depends on wave)
  float hRreg = 0.f;              // w3 only

  // ---------------- phase 0: h = tanh(Xg @ Wg + bg) ----------------
  if (w < 2) {
    float cO = bgO[c];
#pragma unroll 4
    for (int k = 0; k < 40; ++k) cO = fmaf(xS[k], WgO[k * 64 + c], cO);
    float a0 = cO, a1 = cO, a2 = cO, a3 = cO, a4 = cO;
    const int r0 = 1 + w * 5;
#pragma unroll 2
    for (int k = 0; k < 30; ++k) {
      const float wo_ = WgO[(40 + k) * 64 + c];
      a0 = fmaf(xS[(r0 + 0) * 40 + 10 + k], wo_, a0);
      a1 = fmaf(xS[(r0 + 1) * 40 + 10 + k], wo_, a1);
      a2 = fmaf(xS[(r0 + 2) * 40 + 10 + k], wo_, a2);
      a3 = fmaf(xS[(r0 + 3) * 40 + 10 + k], wo_, a3);
      a4 = fmaf(xS[(r0 + 4) * 40 + 10 + k], wo_, a4);
    }
    h0 = tanhf(a0); h1 = tanhf(a1); h2 = tanhf(a2); h3 = tanhf(a3); h4 = tanhf(a4);
    hS[(r0 + 0) * 64 + c] = h0; hS[(r0 + 1) * 64 + c] = h1;
    hS[(r0 + 2) * 64 + c] = h2; hS[(r0 + 3) * 64 + c] = h3;
    hS[(r0 + 4) * 64 + c] = h4;
  } else {
    float cD = bgD[c];
#pragma unroll 4
    for (int k = 0; k < 40; ++k) cD = fmaf(xS[k], WgD[k * 64 + c], cD);
    if (w == 2) {
      float a0 = cD, a1 = cD, a2 = cD, a3 = cD, a4 = cD, a5 = cD;
#pragma unroll 2
      for (int k = 0; k < 30; ++k) {
        const float wd_ = WgD[(40 + k) * 64 + c];
        a0 = fmaf(xS[11 * 40 + 10 + k], wd_, a0);
        a1 = fmaf(xS[12 * 40 + 10 + k], wd_, a1);
        a2 = fmaf(xS[13 * 40 + 10 + k], wd_, a2);
        a3 = fmaf(xS[14 * 40 + 10 + k], wd_, a3);
        a4 = fmaf(xS[15 * 40 + 10 + k], wd_, a4);
        a5 = fmaf(xS[16 * 40 + 10 + k], wd_, a5);
      }
      h0 = tanhf(a0); h1 = tanhf(a1); h2 = tanhf(a2);
      h3 = tanhf(a3); h4 = tanhf(a4); h5 = tanhf(a5);
      hS[11 * 64 + c] = h0; hS[12 * 64 + c] = h1; hS[13 * 64 + c] = h2;
      hS[14 * 64 + c] = h3; hS[15 * 64 + c] = h4; hS[16 * 64 + c] = h5;
    } else {
      float a0 = cD, a1 = cD, a2 = cD, a3 = cD, a4 = cD;
#pragma unroll 2
      for (int k = 0; k < 30; ++k) {
        const float wd_ = WgD[(40 + k) * 64 + c];
        a0 = fmaf(xS[17 * 40 + 10 + k], wd_, a0);
        a1 = fmaf(xS[18 * 40 + 10 + k], wd_, a1);
        a2 = fmaf(xS[19 * 40 + 10 + k], wd_, a2);
        a3 = fmaf(xS[20 * 40 + 10 + k], wd_, a3);
        a4 = fmaf(xS[21 * 40 + 10 + k], wd_, a4);
      }
      h0 = tanhf(a0); h1 = tanhf(a1); h2 = tanhf(a2); h3 = tanhf(a3); h4 = tanhf(a4);
      hS[17 * 64 + c] = h0; hS[18 * 64 + c] = h1; hS[19 * 64 + c] = h2;
      hS[20 * 64 + c] = h3; hS[21 * 64 + c] = h4;
      float aR = bgR[c];
#pragma unroll 4
      for (int k = 0; k < 40; ++k) aR = fmaf(xS[k], WgR[k * 64 + c], aR);
      hRreg = tanhf(aR);
      hS[c] = hRreg;
    }
  }
  __syncthreads();

  const float bmOc = bmO[c], bmDc = bmD[c], bmRc = bmR[c];

  // ---------------- 3 GRU iterations ----------------
  for (int it = 0; it < 3; ++it) {
    const float hRl = hS[c];  // old hR (broadcast source for O seg-1)
    float nn0 = 0.f, nn1 = 0.f, nn2 = 0.f, nn3 = 0.f, nn4 = 0.f, nn5 = 0.f;
    float nRv = 0.f;

    // (a) n-stage: read OTHER gate's OLD h rows from LDS -> own n in regs
    if (w < 2) {
      const float hd0 = hS[11*64+c], hd1 = hS[12*64+c], hd2 = hS[13*64+c];
      const float hd3 = hS[14*64+c], hd4 = hS[15*64+c], hd5 = hS[16*64+c];
      const float hd6 = hS[17*64+c], hd7 = hS[18*64+c], hd8 = hS[19*64+c];
      const float hd9 = hS[20*64+c], hd10 = hS[21*64+c];
      const int a0 = w * 5;
#define NN(s) nn##s = sA2[AODB+(a0+s)*11+0]*hd0 + sA2[AODB+(a0+s)*11+1]*hd1 \
  + sA2[AODB+(a0+s)*11+2]*hd2 + sA2[AODB+(a0+s)*11+3]*hd3 + sA2[AODB+(a0+s)*11+4]*hd4 \
  + sA2[AODB+(a0+s)*11+5]*hd5 + sA2[AODB+(a0+s)*11+6]*hd6 + sA2[AODB+(a0+s)*11+7]*hd7 \
  + sA2[AODB+(a0+s)*11+8]*hd8 + sA2[AODB+(a0+s)*11+9]*hd9 + sA2[AODB+(a0+s)*11+10]*hd10;
      LO(NN)
#undef NN
    } else {
      const float ho0 = hS[1*64+c], ho1 = hS[2*64+c], ho2 = hS[3*64+c];
      const float ho3 = hS[4*64+c], ho4 = hS[5*64+c], ho5 = hS[6*64+c];
      const float ho6 = hS[7*64+c], ho7 = hS[8*64+c], ho8 = hS[9*64+c];
      const float ho9 = hS[10*64+c];
      const int adx = (w == 2) ? 0 : 6;
      if (w == 2) {
#define NN(s) nn##s = sA2[ADOB+(adx+s)*10+0]*ho0 + sA2[ADOB+(adx+s)*10+1]*ho1 \
  + sA2[ADOB+(adx+s)*10+2]*ho2 + sA2[ADOB+(adx+s)*10+3]*ho3 + sA2[ADOB+(adx+s)*10+4]*ho4 \
  + sA2[ADOB+(adx+s)*10+5]*ho5 + sA2[ADOB+(adx+s)*10+6]*ho6 + sA2[ADOB+(adx+s)*10+7]*ho7 \
  + sA2[ADOB+(adx+s)*10+8]*ho8 + sA2[ADOB+(adx+s)*10+9]*ho9;
        L6(NN)
#undef NN
      } else {
#define NN(s) nn##s = sA2[ADOB+(adx+s)*10+0]*ho0 + sA2[ADOB+(adx+s)*10+1]*ho1 \
  + sA2[ADOB+(adx+s)*10+2]*ho2 + sA2[ADOB+(adx+s)*10+3]*ho3 + sA2[ADOB+(adx+s)*10+4]*ho4 \
  + sA2[ADOB+(adx+s)*10+5]*ho5 + sA2[ADOB+(adx+s)*10+6]*ho6 + sA2[ADOB+(adx+s)*10+7]*ho7 \
  + sA2[ADOB+(adx+s)*10+8]*ho8 + sA2[ADOB+(adx+s)*10+9]*ho9;
        LO(NN)
#undef NN
        nRv = sA2[AROB+0]*ho0 + sA2[AROB+1]*ho1 + sA2[AROB+2]*ho2 + sA2[AROB+3]*ho3
            + sA2[AROB+4]*ho4 + sA2[AROB+5]*ho5 + sA2[AROB+6]*ho6 + sA2[AROB+7]*ho7
            + sA2[AROB+8]*ho8 + sA2[AROB+9]*ho9;
      }
    }
    __syncthreads();  // BARRIER A: all old-h reads done before any h write

    // (b) gate compute — pure registers + global weights (readlane broadcasts)
    if (w < 2) {
      const int a0 = w * 5;
      const float aor0 = sA2[AORB+a0+0], aor1 = sA2[AORB+a0+1], aor2 = sA2[AORB+a0+2];
      const float aor3 = sA2[AORB+a0+3], aor4 = sA2[AORB+a0+4];
      float az0=0.f,az1=0.f,az2=0.f,az3=0.f,az4=0.f;
      float ar0=0.f,ar1=0.f,ar2=0.f,ar3=0.f,ar4=0.f;
#pragma unroll 2
      for (int kb = 0; kb < 16; ++kb) {
        const float4 wz = pWzO[kb*64+c], wr = pWrO[kb*64+c];
        const int k4 = kb*4;
#define OPX(s) { const float t0=RLf(h##s,k4), t1=RLf(h##s,k4+1), t2=RLf(h##s,k4+2), t3=RLf(h##s,k4+3); \
  az##s=fmaf(t0,wz.x,az##s); az##s=fmaf(t1,wz.y,az##s); az##s=fmaf(t2,wz.z,az##s); az##s=fmaf(t3,wz.w,az##s); \
  ar##s=fmaf(t0,wr.x,ar##s); ar##s=fmaf(t1,wr.y,ar##s); ar##s=fmaf(t2,wr.z,ar##s); ar##s=fmaf(t3,wr.w,ar##s); }
        LO(OPX)
#undef OPX
      }
#pragma unroll 2
      for (int kb = 16; kb < 32; ++kb) {
        const float4 wz = pWzO[kb*64+c], wr = pWrO[kb*64+c];
        const int k4 = (kb-16)*4;
        const float u0=RLf(hRl,k4), u1=RLf(hRl,k4+1), u2=RLf(hRl,k4+2), u3=RLf(hRl,k4+3);
        const float uz0=u0*wz.x, uz1=u1*wz.y, uz2=u2*wz.z, uz3=u3*wz.w;
        const float ur0=u0*wr.x, ur1=u1*wr.y, ur2=u2*wr.z, ur3=u3*wr.w;
#define OPX(s) { az##s=fmaf(aor##s,uz0,az##s); az##s=fmaf(aor##s,uz1,az##s); \
  az##s=fmaf(aor##s,uz2,az##s); az##s=fmaf(aor##s,uz3,az##s); \
  ar##s=fmaf(aor##s,ur0,ar##s); ar##s=fmaf(aor##s,ur1,ar##s); \
  ar##s=fmaf(aor##s,ur2,ar##s); ar##s=fmaf(aor##s,ur3,ar##s); }
        LO(OPX)
#undef OPX
      }
#pragma unroll 2
      for (int kb = 32; kb < 48; ++kb) {
        const float4 wz = pWzO[kb*64+c], wr = pWrO[kb*64+c];
        const int k4 = (kb-32)*4;
#define OPX(s) { const float t0=RLf(nn##s,k4), t1=RLf(nn##s,k4+1), t2=RLf(nn##s,k4+2), t3=RLf(nn##s,k4+3); \
  az##s=fmaf(t0,wz.x,az##s); az##s=fmaf(t1,wz.y,az##s); az##s=fmaf(t2,wz.z,az##s); az##s=fmaf(t3,wz.w,az##s); \
  ar##s=fmaf(t0,wr.x,ar##s); ar##s=fmaf(t1,wr.y,ar##s); ar##s=fmaf(t2,wr.z,ar##s); ar##s=fmaf(t3,wr.w,ar##s); }
        LO(OPX)
#undef OPX
      }
#define OPX(s) const float z##s = sigmoidf_(az##s); const float hro##s = h##s * sigmoidf_(ar##s);
      LO(OPX)
#undef OPX
      float aS0=bmOc, aS1=bmOc, aS2=bmOc, aS3=bmOc, aS4=bmOc;
#pragma unroll 2
      for (int kb = 0; kb < 16; ++kb) {
        const float4 wm = pWmO[kb*64+c];
        const int k4 = kb*4;
#define OPX(s) { const float t0=RLf(hro##s,k4), t1=RLf(hro##s,k4+1), t2=RLf(hro##s,k4+2), t3=RLf(hro##s,k4+3); \
  aS##s=fmaf(t0,wm.x,aS##s); aS##s=fmaf(t1,wm.y,aS##s); aS##s=fmaf(t2,wm.z,aS##s); aS##s=fmaf(t3,wm.w,aS##s); }
        LO(OPX)
#undef OPX
      }
#pragma unroll 2
      for (int kb = 16; kb < 32; ++kb) {
        const float4 wm = pWmO[kb*64+c];
        const int k4 = (kb-16)*4;
        const float u0=RLf(hRl,k4), u1=RLf(hRl,k4+1), u2=RLf(hRl,k4+2), u3=RLf(hRl,k4+3);
        const float um0=u0*wm.x, um1=u1*wm.y, um2=u2*wm.z, um3=u3*wm.w;
#define OPX(s) { aS##s=fmaf(aor##s,um0,aS##s); aS##s=fmaf(aor##s,um1,aS##s); \
  aS##s=fmaf(aor##s,um2,aS##s); aS##s=fmaf(aor##s,um3,aS##s); }
        LO(OPX)
#undef OPX
      }
#pragma unroll 2
      for (int kb = 32; kb < 48; ++kb) {
        const float4 wm = pWmO[kb*64+c];
        const int k4 = (kb-32)*4;
#define OPX(s) { const float t0=RLf(nn##s,k4), t1=RLf(nn##s,k4+1), t2=RLf(nn##s,k4+2), t3=RLf(nn##s,k4+3); \
  aS##s=fmaf(t0,wm.x,aS##s); aS##s=fmaf(t1,wm.y,aS##s); aS##s=fmaf(t2,wm.z,aS##s); aS##s=fmaf(t3,wm.w,aS##s); }
        LO(OPX)
#undef OPX
      }
      const int r0 = 1 + a0;
#define OPX(s) { h##s = (1.f - z##s)*h##s + z##s*tanhf(aS##s); hS[(r0+s)*64+c] = h##s; }
      LO(OPX)
#undef OPX
    } else if (w == 2) {
      float az0=0.f,az1=0.f,az2=0.f,az3=0.f,az4=0.f,az5=0.f;
      float ar0=0.f,ar1=0.f,ar2=0.f,ar3=0.f,ar4=0.f,ar5=0.f;
#pragma unroll 2
      for (int kb = 0; kb < 16; ++kb) {
        const float4 wz = pWzD[kb*64+c], wr = pWrD[kb*64+c];
        const int k4 = kb*4;
#define OPX(s) { const float t0=RLf(h##s,k4), t1=RLf(h##s,k4+1), t2=RLf(h##s,k4+2), t3=RLf(h##s,k4+3); \
  az##s=fmaf(t0,wz.x,az##s); az##s=fmaf(t1,wz.y,az##s); az##s=fmaf(t2,wz.z,az##s); az##s=fmaf(t3,wz.w,az##s); \
  ar##s=fmaf(t0,wr.x,ar##s); ar##s=fmaf(t1,wr.y,ar##s); ar##s=fmaf(t2,wr.z,ar##s); ar##s=fmaf(t3,wr.w,ar##s); }
        L6(OPX)
#undef OPX
      }
#pragma unroll 2
      for (int kb = 16; kb < 32; ++kb) {
        const float4 wz = pWzD[kb*64+c], wr = pWrD[kb*64+c];
        const int k4 = (kb-16)*4;
#define OPX(s) { const float t0=RLf(nn##s,k4), t1=RLf(nn##s,k4+1), t2=RLf(nn##s,k4+2), t3=RLf(nn##s,k4+3); \
  az##s=fmaf(t0,wz.x,az##s); az##s=fmaf(t1,wz.y,az##s); az##s=fmaf(t2,wz.z,az##s); az##s=fmaf(t3,wz.w,az##s); \
  ar##s=fmaf(t0,wr.x,ar##s); ar##s=fmaf(t1,wr.y,ar##s); ar##s=fmaf(t2,wr.z,ar##s); ar##s=fmaf(t3,wr.w,ar##s); }
        L6(OPX)
#undef OPX
      }
#define OPX(s) const float z##s = sigmoidf_(az##s); const float hrd##s = h##s * sigmoidf_(ar##s);
      L6(OPX)
#undef OPX
      float aS0=bmDc, aS1=bmDc, aS2=bmDc, aS3=bmDc, aS4=bmDc, aS5=bmDc;
#pragma unroll 2
      for (int kb = 0; kb < 16; ++kb) {
        const float4 wm = pWmD[kb*64+c];
        const int k4 = kb*4;
#define OPX(s) { const float t0=RLf(hrd##s,k4), t1=RLf(hrd##s,k4+1), t2=RLf(hrd##s,k4+2), t3=RLf(hrd##s,k4+3); \
  aS##s=fmaf(t0,wm.x,aS##s); aS##s=fmaf(t1,wm.y,aS##s); aS##s=fmaf(t2,wm.z,aS##s); aS##s=fmaf(t3,wm.w,aS##s); }
        L6(OPX)
#undef OPX
      }
#pragma unroll 2
      for (int kb = 16; kb < 32; ++kb) {
        const float4 wm = pWmD[kb*64+c];
        const int k4 = (kb-16)*4;
#define OPX(s) { const float t0=RLf(nn##s,k4), t1=RLf(nn##s,k4+1), t2=RLf(nn##s,k4+2), t3=RLf(nn##s,k4+3); \
  aS##s=fmaf(t0,wm.x,aS##s); aS##s=fmaf(t1,wm.y,aS##s); aS##s=fmaf(t2,wm.z,aS##s); aS##s=fmaf(t3,wm.w,aS##s); }
        L6(OPX)
#undef OPX
      }
#define OPX(s) { h##s = (1.f - z##s)*h##s + z##s*tanhf(aS##s); hS[(11+s)*64+c] = h##s; }
      L6(OPX)
#undef OPX
    } else {
      // w3: D rows 6-10 (slots 0-4) + gate R
      float az0=0.f,az1=0.f,az2=0.f,az3=0.f,az4=0.f;
      float ar0=0.f,ar1=0.f,ar2=0.f,ar3=0.f,ar4=0.f;
      float azr = 0.f, arr = 0.f;
#pragma unroll 2
      for (int kb = 0; kb < 16; ++kb) {
        const float4 wz = pWzD[kb*64+c], wr = pWrD[kb*64+c];
        const int k4 = kb*4;
#define OPX(s) { const float t0=RLf(h##s,k4), t1=RLf(h##s,k4+1), t2=RLf(h##s,k4+2), t3=RLf(h##s,k4+3); \
  az##s=fmaf(t0,wz.x,az##s); az##s=fmaf(t1,wz.y,az##s); az##s=fmaf(t2,wz.z,az##s); az##s=fmaf(t3,wz.w,az##s); \
  ar##s=fmaf(t0,wr.x,ar##s); ar##s=fmaf(t1,wr.y,ar##s); ar##s=fmaf(t2,wr.z,ar##s); ar##s=fmaf(t3,wr.w,ar##s); }
        LO(OPX)
#undef OPX
        const float4 wzr = pWzR[kb*64+c], wrr = pWrR[kb*64+c];
        const float q0=RLf(hRreg,k4), q1=RLf(hRreg,k4+1), q2=RLf(hRreg,k4+2), q3=RLf(hRreg,k4+3);
        azr=fmaf(q0,wzr.x,azr); azr=fmaf(q1,wzr.y,azr); azr=fmaf(q2,wzr.z,azr); azr=fmaf(q3,wzr.w,azr);
        arr=fmaf(q0,wrr.x,arr); arr=fmaf(q1,wrr.y,arr); arr=fmaf(q2,wrr.z,arr); arr=fmaf(q3,wrr.w,arr);
      }
#pragma unroll 2
      for (int kb = 16; kb < 32; ++kb) {
        const float4 wz = pWzD[kb*64+c], wr = pWrD[kb*64+c];
        const int k4 = (kb-16)*4;
#define OPX(s) { const float t0=RLf(nn##s,k4), t1=RLf(nn##s,k4+1), t2=RLf(nn##s,k4+2), t3=RLf(nn##s,k4+3); \
  az##s=fmaf(t0,wz.x,az##s); az##s=fmaf(t1,wz.y,az##s); az##s=fmaf(t2,wz.z,az##s); az##s=fmaf(t3,wz.w,az##s); \
  ar##s=fmaf(t0,wr.x,ar##s); ar##s=fmaf(t1,wr.y,ar##s); ar##s=fmaf(t2,wr.z,ar##s); ar##s=fmaf(t3,wr.w,ar##s); }
        LO(OPX)
#undef OPX
        const float4 wzr = pWzR[kb*64+c], wrr = pWrR[kb*64+c];
        const float q0=RLf(nRv,k4), q1=RLf(nRv,k4+1), q2=RLf(nRv,k4+2), q3=RLf(nRv,k4+3);
        azr=fmaf(q0,wzr.x,azr); azr=fmaf(q1,wzr.y,azr); azr=fmaf(q2,wzr.z,azr); azr=fmaf(q3,wzr.w,azr);
        arr=fmaf(q0,wrr.x,arr); arr=fmaf(q1,wrr.y,arr); arr=fmaf(q2,wrr.z,arr); arr=fmaf(q3,wrr.w,arr);
      }
#define OPX(s) const float z##s = sigmoidf_(az##s); const float hrd##s = h##s * sigmoidf_(ar##s);
      LO(OPX)
#undef OPX
      const float zr = sigmoidf_(azr);
      const float hrr = hRreg * sigmoidf_(arr);
      float aS0=bmDc, aS1=bmDc, aS2=bmDc, aS3=bmDc, aS4=bmDc;
      float amr = bmRc;
#pragma unroll 2
      for (int kb = 0; kb < 16; ++kb) {
        const float4 wm = pWmD[kb*64+c];
        const int k4 = kb*4;
#define OPX(s) { const float t0=RLf(hrd##s,k4), t1=RLf(hrd##s,k4+1), t2=RLf(hrd##s,k4+2), t3=RLf(hrd##s,k4+3); \
  aS##s=fmaf(t0,wm.x,aS##s); aS##s=fmaf(t1,wm.y,aS##s); aS##s=fmaf(t2,wm.z,aS##s); aS##s=fmaf(t3,wm.w,aS##s); }
        LO(OPX)
#undef OPX
        const float4 wmr = pWmR[kb*64+c];
        const float q0=RLf(hrr,k4), q1=RLf(hrr,k4+1), q2=RLf(hrr,k4+2), q3=RLf(hrr,k4+3);
        amr=fmaf(q0,wmr.x,amr); amr=fmaf(q1,wmr.y,amr); amr=fmaf(q2,wmr.z,amr); amr=fmaf(q3,wmr.w,amr);
      }
#pragma unroll 2
      for (int kb = 16; kb < 32; ++kb) {
        const float4 wm = pWmD[kb*64+c];
        const int k4 = (kb-16)*4;
#define OPX(s) { const float t0=RLf(nn##s,k4), t1=RLf(nn##s,k4+1), t2=RLf(nn##s,k4+2), t3=RLf(nn##s,k4+3); \
  aS##s=fmaf(t0,wm.x,aS##s); aS##s=fmaf(t1,wm.y,aS##s); aS##s=fmaf(t2,wm.z,aS##s); aS##s=fmaf(t3,wm.w,aS##s); }
        LO(OPX)
#undef OPX
        const float4 wmr = pWmR[kb*64+c];
        const float q0=RLf(nRv,k4), q1=RLf(nRv,k4+1), q2=RLf(nRv,k4+2), q3=RLf(nRv,k4+3);
        amr=fmaf(q0,wmr.x,amr); amr=fmaf(q1,wmr.y,amr); amr=fmaf(q2,wmr.z,amr); amr=fmaf(q3,wmr.w,amr);
      }
#define OPX(s) { h##s = (1.f - z##s)*h##s + z##s*tanhf(aS##s); hS[(17+s)*64+c] = h##s; }
      LO(OPX)
#undef OPX
      hRreg = (1.f - zr) * hRreg + zr * tanhf(amr);
      hS[c] = hRreg;
    }
    __syncthreads();  // BARRIER B: new h visible
  }

  // ---------------- scores (rows per wave) ----------------
  const int g = c >> 4;
  const int c1 = c & 15;
  float pR = 0.f, pO = 0.f, pD = 0.f;
  int lo, hi;
  if      (w == 0) { lo = 1;  hi = 6;  }
  else if (w == 1) { lo = 6;  hi = 11; }
  else if (w == 2) { lo = 11; hi = 17; }
  else             { lo = 17; hi = 22; }
  for (int rr = lo + g; rr < hi; rr += 4) {
    const float* W1; const float* b1; const float* W2;
    if (rr < 11) { W1 = W1O; b1 = b1O; W2 = W2O; }
    else         { W1 = W1D; b1 = b1D; W2 = W2D; }
    float a = b1[c1];
#pragma unroll 8
    for (int kk = 0; kk < 64; ++kk) {
      const int k = (kk + (g << 4)) & 63;
      a = fmaf(hS[rr * 64 + k], W1[k * 16 + c1], a);
    }
    const float t = tanhf(a) * W2[c1];
    if (rr < 11) pO += t;
    else pD += t;
  }
  if (w == 3 && g == 0) {  // row 0 (R branch)
    float a = b1R[c1];
#pragma unroll 8
    for (int kk = 0; kk < 64; ++kk) {
      a = fmaf(hS[kk], W1R[kk * 16 + c1], a);
    }
    pR = tanhf(a) * W2R[c1];
  }
#pragma unroll
  for (int off = 32; off >= 1; off >>= 1) {
    pR += __shfl_xor(pR, off, 64);
    pO += __shfl_xor(pO, off, 64);
    pD += __shfl_xor(pD, off, 64);
  }
  if (c == 0) { red[w * 4 + 0] = pR; red[w * 4 + 1] = pO; red[w * 4 + 2] = pD; }
  __syncthreads();
  if (w == 0 && c < 60) {
    const float PR = red[0] + red[4] + red[8]  + red[12];
    const float PO = red[1] + red[5] + red[9]  + red[13];
    const float PD = red[2] + red[6] + red[10] + red[14];
    out[(size_t)b * 60 + c] = PR * tp[c] + PO * tp[60 + c] + PD * tp[120 + c];
  }
}

extern "C" void kernel_launch(void* const* d_in, const int* in_sizes, int n_in,
                              void* d_out, int out_size, void* d_ws, size_t ws_size,
                              hipStream_t stream) {
  const float* X   = (const float*)d_in[0];
  const float* A   = (const float*)d_in[1];
  const float* WgR = (const float*)d_in[2];
  const float* bgR = (const float*)d_in[3];
  const float* WgO = (const float*)d_in[4];
  const float* bgO = (const float*)d_in[5];
  const float* WgD = (const float*)d_in[6];
  const float* bgD = (const float*)d_in[7];
  const float* WzR = (const float*)d_in[8];
  const float* WrR = (const float*)d_in[9];
  const float* WmR = (const float*)d_in[10];
  const float* bmR = (const float*)d_in[11];
  const float* WzO = (const float*)d_in[12];
  const float* WrO = (const float*)d_in[13];
  const float* WmO = (const float*)d_in[14];
  const float* bmO = (const float*)d_in[15];
  const float* WzD = (const float*)d_in[16];
  const float* WrD = (const float*)d_in[17];
  const float* WmD = (const float*)d_in[18];
  const float* bmD = (const float*)d_in[19];
  const float* W1R = (const float*)d_in[20];
  const float* b1R = (const float*)d_in[21];
  const float* W2R = (const float*)d_in[22];
  const float* W1O = (const float*)d_in[23];
  const float* b1O = (const float*)d_in[24];
  const float* W2O = (const float*)d_in[25];
  const float* W1D = (const float*)d_in[26];
  const float* b1D = (const float*)d_in[27];
  const float* W2D = (const float*)d_in[28];
  const float* Tmp = (const float*)d_in[29];
  const float* GK  = (const float*)d_in[30];
  const float* GRK = (const float*)d_in[31];
  const float* GB  = (const float*)d_in[32];
  const float* WO  = (const float*)d_in[33];
  const int*   IDX = (const int*)d_in[34];

  float* tp = (float*)d_ws;  // 3*60 floats in the first 1KB
  char*  ws = (char*)d_ws;
  const int B = in_sizes[0] / 880;

  hipLaunchKernelGGL(temporal_kernel, dim3(1), dim3(64), 0, stream, Tmp, GK, GRK, GB, WO, IDX, tp);
  hipLaunchKernelGGL(prep_kernel, dim3(336), dim3(64), 0, stream,
                     WzR, WrR, WmR, WzO, WrO, WmO, WzD, WrD, WmD, ws);
  hipLaunchKernelGGL(ggnn_main, dim3(B), dim3(256), 0, stream,
                     X, A, WgR, bgR, WgO, bgO, WgD, bgD,
                     bmR, bmO, bmD,
                     W1R, b1R, W2R, W1O, b1O, W2O, W1D, b1D, W2D,
                     (const char*)ws, (const float*)tp, (float*)d_out);
}

// Round 17
// 991.315 us; speedup vs baseline: 1.0539x; 1.0539x over previous
//
#include <hip/hip_runtime.h>
#include <hip/hip_bf16.h>
#include <math.h>

#define DEV __device__ __forceinline__

DEV float sigmoidf_(float x) { return 1.0f / (1.0f + __expf(-x)); }

// Broadcast lane `lane` (wave-uniform index) of v to all lanes (VALU path).
DEV float RLf(float v, int lane) {
  return __int_as_float(__builtin_amdgcn_readlane(__float_as_int(v), lane));
}

// (slot, row) lists: slot = per-wave accumulator index, row = local gate row
#define L5A(OP) OP(0,0) OP(1,1) OP(2,2) OP(3,3) OP(4,4)
#define L5B(OP) OP(0,5) OP(1,6) OP(2,7) OP(3,8) OP(4,9)
#define L6A(OP) OP(0,0) OP(1,1) OP(2,2) OP(3,3) OP(4,4) OP(5,5)
#define L5D(OP) OP(0,6) OP(1,7) OP(2,8) OP(3,9) OP(4,10)

// Compact A staging (240 used entries of the 22x22 matrix)
#define AROB 0
#define AORB 16
#define AODB 32
#define ADOB 144
#define ANUM 256

DEV float gstep(float x, float h, const float* k, const float* rk, const float* bb) {
  const float z  = sigmoidf_(fmaf(x, k[0], bb[0]) + fmaf(h, rk[0], bb[3]));
  const float r  = sigmoidf_(fmaf(x, k[1], bb[1]) + fmaf(h, rk[1], bb[4]));
  const float hh = tanhf(fmaf(x, k[2], bb[2]) + r * fmaf(h, rk[2], bb[5]));
  return z * h + (1.f - z) * hh;
}

__global__ void __launch_bounds__(64, 1)
temporal_kernel(const float* __restrict__ T, const float* __restrict__ GK,
                const float* __restrict__ GRK, const float* __restrict__ GB,
                const float* __restrict__ WO, const int* __restrict__ IDX,
                float* __restrict__ tp) {
  const int i = threadIdx.x;
  __shared__ float fb[3][75];
  __shared__ float gg[3][75];
  if (i < 3) {
    float k0[3], k1[3], rk0[3], rk1[3];
#pragma unroll
    for (int q = 0; q < 3; ++q) {
      k0[q]  = GK[i * 6 + q];      k1[q]  = GK[i * 6 + 3 + q];
      rk0[q] = GRK[i * 6 + q];     rk1[q] = GRK[i * 6 + 3 + q];
    }
    const float* B0 = GB + i * 12;
    const float* B1 = GB + i * 12 + 6;
    float h = 0.f;
    for (int s = 0; s < 75; ++s) { h = gstep(T[i * 75 + s], h, k0, rk0, B0); fb[i][s] = h; }
    h = 0.f;
    for (int s = 0; s < 75; ++s) { h = gstep(fb[i][74 - s], h, k1, rk1, B1); gg[i][s] = h; }
    const float wo = WO[i];
    float mx = -1e30f;
    for (int s = 0; s < 75; ++s) mx = fmaxf(mx, gg[i][s] * wo);
    float sum = 0.f;
    for (int s = 0; s < 75; ++s) { const float e = __expf(gg[i][s] * wo - mx); fb[i][s] = e; sum += e; }
    const float inv = 1.f / sum;
    for (int j = 0; j < 60; ++j) tp[i * 60 + j] = fb[i][IDX[j]] * inv;
  }
}

// Weight repack (proven R13): lane c's 4 consecutive k-values as one dwordx4.
// ws layout (1KB/k4-block): ZR[0..31] RR[32..63] MR[64..95] ZO[96..143]
// RO[144..191] MO[192..239] ZD[240..271] RD[272..303] MD[304..335]
__global__ void __launch_bounds__(64, 1) prep_kernel(
    const float* __restrict__ WzR, const float* __restrict__ WrR, const float* __restrict__ WmR,
    const float* __restrict__ WzO, const float* __restrict__ WrO, const float* __restrict__ WmO,
    const float* __restrict__ WzD, const float* __restrict__ WrD, const float* __restrict__ WmD,
    char* __restrict__ ws) {
  const int fi = blockIdx.x;
  const int c = threadIdx.x;
  const float* W; int base;
  if      (fi <  32) { W = WzR; base = 0;   }
  else if (fi <  64) { W = WrR; base = 32;  }
  else if (fi <  96) { W = WmR; base = 64;  }
  else if (fi < 144) { W = WzO; base = 96;  }
  else if (fi < 192) { W = WrO; base = 144; }
  else if (fi < 240) { W = WmO; base = 192; }
  else if (fi < 272) { W = WzD; base = 240; }
  else if (fi < 304) { W = WrD; base = 272; }
  else               { W = WmD; base = 304; }
  const int kb = fi - base;
  float4 v;
  v.x = W[(kb * 4 + 0) * 64 + c];
  v.y = W[(kb * 4 + 1) * 64 + c];
  v.z = W[(kb * 4 + 2) * 64 + c];
  v.w = W[(kb * 4 + 3) * 64 + c];
  *(float4*)(ws + 1024 + (size_t)fi * 1024 + c * 16) = v;
}

// ---- per-row macro bodies (s=slot, i=local row) ----
#define ZRDECL(s,i) float az##s = 0.f, ar##s = 0.f;
#define AORD(s,i)  const float aor##s = sA2[AORB + (i)];
#define OS0(s,i) { const float4 v = *reinterpret_cast<const float4*>(&hS[(1+(i))*64 + kb*4]); \
  az##s=fmaf(v.x,wz.x,az##s); az##s=fmaf(v.y,wz.y,az##s); az##s=fmaf(v.z,wz.z,az##s); az##s=fmaf(v.w,wz.w,az##s); \
  ar##s=fmaf(v.x,wr.x,ar##s); ar##s=fmaf(v.y,wr.y,ar##s); ar##s=fmaf(v.z,wr.z,ar##s); ar##s=fmaf(v.w,wr.w,ar##s); }
#define OS1(s,i) { az##s=fmaf(aor##s,uz.x,az##s); az##s=fmaf(aor##s,uz.y,az##s); \
  az##s=fmaf(aor##s,uz.z,az##s); az##s=fmaf(aor##s,uz.w,az##s); \
  ar##s=fmaf(aor##s,ur.x,ar##s); ar##s=fmaf(aor##s,ur.y,ar##s); \
  ar##s=fmaf(aor##s,ur.z,ar##s); ar##s=fmaf(aor##s,ur.w,ar##s); }
#define OS2(s,i) { const float4 v = *reinterpret_cast<const float4*>(&nS[(1+(i))*64 + (kb-32)*4]); \
  az##s=fmaf(v.x,wz.x,az##s); az##s=fmaf(v.y,wz.y,az##s); az##s=fmaf(v.z,wz.z,az##s); az##s=fmaf(v.w,wz.w,az##s); \
  ar##s=fmaf(v.x,wr.x,ar##s); ar##s=fmaf(v.y,wr.y,ar##s); ar##s=fmaf(v.z,wr.z,ar##s); ar##s=fmaf(v.w,wr.w,ar##s); }
#define OSIG(s,i) zS##s = sigmoidf_(az##s); const float rr##s = sigmoidf_(ar##s);
#define OGST(s,i) gS[(1+(i))*64+c] = hS[(1+(i))*64+c] * rr##s;
#define OAMD(s,i) aS##s = bmOc;
#define OM0(s,i) { const float4 v = *reinterpret_cast<const float4*>(&gS[(1+(i))*64 + kb*4]); \
  aS##s=fmaf(v.x,wm.x,aS##s); aS##s=fmaf(v.y,wm.y,aS##s); aS##s=fmaf(v.z,wm.z,aS##s); aS##s=fmaf(v.w,wm.w,aS##s); }
#define OM1(s,i) { aS##s=fmaf(aor##s,um.x,aS##s); aS##s=fmaf(aor##s,um.y,aS##s); \
  aS##s=fmaf(aor##s,um.z,aS##s); aS##s=fmaf(aor##s,um.w,aS##s); }
// HYBRID: m-pass n-segment via readlane from nn regs (kills ~80-96 LDS
// broadcasts/wave/iter; nn computed in-register at n-stage anyway).
#define OM2R(s,i) { const float t0=RLf(nn##s,k4), t1=RLf(nn##s,k4+1), t2=RLf(nn##s,k4+2), t3=RLf(nn##s,k4+3); \
  aS##s=fmaf(t0,wm.x,aS##s); aS##s=fmaf(t1,wm.y,aS##s); aS##s=fmaf(t2,wm.z,aS##s); aS##s=fmaf(t3,wm.w,aS##s); }

#define DS0(s,i) { const float4 v = *reinterpret_cast<const float4*>(&hS[(11+(i))*64 + kb*4]); \
  az##s=fmaf(v.x,wz.x,az##s); az##s=fmaf(v.y,wz.y,az##s); az##s=fmaf(v.z,wz.z,az##s); az##s=fmaf(v.w,wz.w,az##s); \
  ar##s=fmaf(v.x,wr.x,ar##s); ar##s=fmaf(v.y,wr.y,ar##s); ar##s=fmaf(v.z,wr.z,ar##s); ar##s=fmaf(v.w,wr.w,ar##s); }
#define DS1(s,i) { const float4 v = *reinterpret_cast<const float4*>(&nS[(11+(i))*64 + (kb-16)*4]); \
  az##s=fmaf(v.x,wz.x,az##s); az##s=fmaf(v.y,wz.y,az##s); az##s=fmaf(v.z,wz.z,az##s); az##s=fmaf(v.w,wz.w,az##s); \
  ar##s=fmaf(v.x,wr.x,ar##s); ar##s=fmaf(v.y,wr.y,ar##s); ar##s=fmaf(v.z,wr.z,ar##s); ar##s=fmaf(v.w,wr.w,ar##s); }
#define DSIG(s,i) zS##s = sigmoidf_(az##s); const float rr##s = sigmoidf_(ar##s);
#define DGST(s,i) gS[(11+(i))*64+c] = hS[(11+(i))*64+c] * rr##s;
#define DAMD(s,i) aS##s = bmDc;
#define DM0(s,i) { const float4 v = *reinterpret_cast<const float4*>(&gS[(11+(i))*64 + kb*4]); \
  aS##s=fmaf(v.x,wm.x,aS##s); aS##s=fmaf(v.y,wm.y,aS##s); aS##s=fmaf(v.z,wm.z,aS##s); aS##s=fmaf(v.w,wm.w,aS##s); }
#define DM1R(s,i) { const float t0=RLf(nn##s,k4), t1=RLf(nn##s,k4+1), t2=RLf(nn##s,k4+2), t3=RLf(nn##s,k4+3); \
  aS##s=fmaf(t0,wm.x,aS##s); aS##s=fmaf(t1,wm.y,aS##s); aS##s=fmaf(t2,wm.z,aS##s); aS##s=fmaf(t3,wm.w,aS##s); }

#define OGATE(LIST) { \
  LIST(ZRDECL) LIST(AORD) \
  _Pragma("unroll 2") for (int kb = 0; kb < 16; ++kb) { \
    const float4 wz = pWzO[kb*64+c], wr = pWrO[kb*64+c]; LIST(OS0) } \
  _Pragma("unroll 2") for (int kb = 16; kb < 32; ++kb) { \
    const float4 wz = pWzO[kb*64+c], wr = pWrO[kb*64+c]; \
    const float4 h0 = *reinterpret_cast<const float4*>(&hS[(kb-16)*4]); \
    float4 uz, ur; \
    uz.x=h0.x*wz.x; uz.y=h0.y*wz.y; uz.z=h0.z*wz.z; uz.w=h0.w*wz.w; \
    ur.x=h0.x*wr.x; ur.y=h0.y*wr.y; ur.z=h0.z*wr.z; ur.w=h0.w*wr.w; \
    LIST(OS1) } \
  _Pragma("unroll 2") for (int kb = 32; kb < 48; ++kb) { \
    const float4 wz = pWzO[kb*64+c], wr = pWrO[kb*64+c]; LIST(OS2) } \
  LIST(OSIG) LIST(OGST) LIST(OAMD) \
  _Pragma("unroll 2") for (int kb = 0; kb < 16; ++kb) { \
    const float4 wm = pWmO[kb*64+c]; LIST(OM0) } \
  _Pragma("unroll 2") for (int kb = 16; kb < 32; ++kb) { \
    const float4 wm = pWmO[kb*64+c]; \
    const float4 h0 = *reinterpret_cast<const float4*>(&hS[(kb-16)*4]); \
    float4 um; um.x=h0.x*wm.x; um.y=h0.y*wm.y; um.z=h0.z*wm.z; um.w=h0.w*wm.w; \
    LIST(OM1) } \
  _Pragma("unroll 2") for (int kb = 32; kb < 48; ++kb) { \
    const float4 wm = pWmO[kb*64+c]; const int k4 = (kb-32)*4; LIST(OM2R) } }

#define DGATE(LIST) { \
  LIST(ZRDECL) \
  _Pragma("unroll 2") for (int kb = 0; kb < 16; ++kb) { \
    const float4 wz = pWzD[kb*64+c], wr = pWrD[kb*64+c]; LIST(DS0) } \
  _Pragma("unroll 2") for (int kb = 16; kb < 32; ++kb) { \
    const float4 wz = pWzD[kb*64+c], wr = pWrD[kb*64+c]; LIST(DS1) } \
  LIST(DSIG) LIST(DGST) LIST(DAMD) \
  _Pragma("unroll 2") for (int kb = 0; kb < 16; ++kb) { \
    const float4 wm = pWmD[kb*64+c]; LIST(DM0) } \
  _Pragma("unroll 2") for (int kb = 16; kb < 32; ++kb) { \
    const float4 wm = pWmD[kb*64+c]; const int k4 = (kb-16)*4; LIST(DM1R) } }

#define OUPD(s,i) { const float h_ = hS[(1+(i))*64+c]; \
  hS[(1+(i))*64+c] = (1.f - zS##s)*h_ + zS##s*tanhf(aS##s); }
#define DUPD(s,i) { const float h_ = hS[(11+(i))*64+c]; \
  hS[(11+(i))*64+c] = (1.f - zS##s)*h_ + zS##s*tanhf(aS##s); }

// n-stage: compute into REGISTERS (kept live for m-pass readlane) AND write
// nS (still read by the z/r pass via LDS).
#define NSO(s,i) nn##s = \
  sA2[AODB+(i)*11+0]*hd0 + sA2[AODB+(i)*11+1]*hd1 + sA2[AODB+(i)*11+2]*hd2 + sA2[AODB+(i)*11+3]*hd3 \
+ sA2[AODB+(i)*11+4]*hd4 + sA2[AODB+(i)*11+5]*hd5 + sA2[AODB+(i)*11+6]*hd6 + sA2[AODB+(i)*11+7]*hd7 \
+ sA2[AODB+(i)*11+8]*hd8 + sA2[AODB+(i)*11+9]*hd9 + sA2[AODB+(i)*11+10]*hd10; \
  nS[(1+(i))*64+c] = nn##s;
#define NSD(s,i) nn##s = \
  sA2[ADOB+(i)*10+0]*ho0 + sA2[ADOB+(i)*10+1]*ho1 + sA2[ADOB+(i)*10+2]*ho2 + sA2[ADOB+(i)*10+3]*ho3 \
+ sA2[ADOB+(i)*10+4]*ho4 + sA2[ADOB+(i)*10+5]*ho5 + sA2[ADOB+(i)*10+6]*ho6 + sA2[ADOB+(i)*10+7]*ho7 \
+ sA2[ADOB+(i)*10+8]*ho8 + sA2[ADOB+(i)*10+9]*ho9; \
  nS[(11+(i))*64+c] = nn##s;

// 256 threads = 4 waves on ONE batch element; h in LDS; rows per wave
// (w0: O 0-4, w1: O 5-9, w2: D 0-5, w3: D 6-10 + R). HYBRID operand feeds:
// z/r + m g-segment via LDS broadcasts, m n-segment via readlane from regs
// — balances the single LDS pipe (R15: saturated at 829us) against the VALU
// (R16 full-RL: saturated at 1044us).
__global__ void __launch_bounds__(256) ggnn_main(
    const float* __restrict__ X, const float* __restrict__ A,
    const float* __restrict__ WgR, const float* __restrict__ bgR,
    const float* __restrict__ WgO, const float* __restrict__ bgO,
    const float* __restrict__ WgD, const float* __restrict__ bgD,
    const float* __restrict__ bmR, const float* __restrict__ bmO, const float* __restrict__ bmD,
    const float* __restrict__ W1R, const float* __restrict__ b1R, const float* __restrict__ W2R,
    const float* __restrict__ W1O, const float* __restrict__ b1O, const float* __restrict__ W2O,
    const float* __restrict__ W1D, const float* __restrict__ b1D, const float* __restrict__ W2D,
    const char* __restrict__ ws, const float* __restrict__ tp,
    float* __restrict__ out) {
  const int b = blockIdx.x;
  const int w = threadIdx.x >> 6;
  const int c = threadIdx.x & 63;
  const int tid = threadIdx.x;

  __shared__ __align__(16) float hS[22 * 64];  // h rows: 0=R, 1-10=O, 11-21=D
  __shared__ __align__(16) float nS[22 * 64];  // staged n, same row order
  __shared__ __align__(16) float gS[22 * 64];  // h*r staging; X stage at init
  __shared__ float sA2[ANUM];
  __shared__ float red[16];

  const float4* pk = (const float4*)(ws + 1024);
  const float4* pWzR = pk + 0   * 64;
  const float4* pWrR = pk + 32  * 64;
  const float4* pWmR = pk + 64  * 64;
  const float4* pWzO = pk + 96  * 64;
  const float4* pWrO = pk + 144 * 64;
  const float4* pWmO = pk + 192 * 64;
  const float4* pWzD = pk + 240 * 64;
  const float4* pWrD = pk + 272 * 64;
  const float4* pWmD = pk + 304 * 64;

  const float* Xb = X + (size_t)b * 880;
  const float* Ab = A + (size_t)b * 484;
  for (int t = tid; t < 880; t += 256) gS[t] = Xb[t];
  if (tid < 10) {
    sA2[AROB + tid] = Ab[1 + tid];
    sA2[AORB + tid] = Ab[(1 + tid) * 22];
  }
  for (int t = tid; t < 110; t += 256) {
    const int i = t / 11, j = t - i * 11;
    sA2[AODB + t] = Ab[(1 + i) * 22 + 11 + j];
  }
  for (int t = tid; t < 110; t += 256) {
    const int i = t / 10, j = t - i * 10;
    sA2[ADOB + t] = Ab[(11 + i) * 22 + 1 + j];
  }
  __syncthreads();

  // ---------------- phase 0: h = tanh(Xg @ Wg + bg), rows per wave ----------
  if (w == 0 || w == 1) {
    float cO = bgO[c];
#pragma unroll 4
    for (int k = 0; k < 40; ++k) cO = fmaf(gS[k], WgO[k * 64 + c], cO);
    float a0 = cO, a1 = cO, a2 = cO, a3 = cO, a4 = cO;
    const int r0 = (w == 0) ? 1 : 6;
#pragma unroll 2
    for (int k = 0; k < 30; ++k) {
      const float wo_ = WgO[(40 + k) * 64 + c];
      a0 = fmaf(gS[(r0 + 0) * 40 + 10 + k], wo_, a0);
      a1 = fmaf(gS[(r0 + 1) * 40 + 10 + k], wo_, a1);
      a2 = fmaf(gS[(r0 + 2) * 40 + 10 + k], wo_, a2);
      a3 = fmaf(gS[(r0 + 3) * 40 + 10 + k], wo_, a3);
      a4 = fmaf(gS[(r0 + 4) * 40 + 10 + k], wo_, a4);
    }
    hS[(r0 + 0) * 64 + c] = tanhf(a0);
    hS[(r0 + 1) * 64 + c] = tanhf(a1);
    hS[(r0 + 2) * 64 + c] = tanhf(a2);
    hS[(r0 + 3) * 64 + c] = tanhf(a3);
    hS[(r0 + 4) * 64 + c] = tanhf(a4);
  } else {
    float cD = bgD[c];
#pragma unroll 4
    for (int k = 0; k < 40; ++k) cD = fmaf(gS[k], WgD[k * 64 + c], cD);
    if (w == 2) {
      float a0 = cD, a1 = cD, a2 = cD, a3 = cD, a4 = cD, a5 = cD;
#pragma unroll 2
      for (int k = 0; k < 30; ++k) {
        const float wd_ = WgD[(40 + k) * 64 + c];
        a0 = fmaf(gS[11 * 40 + 10 + k], wd_, a0);
        a1 = fmaf(gS[12 * 40 + 10 + k], wd_, a1);
        a2 = fmaf(gS[13 * 40 + 10 + k], wd_, a2);
        a3 = fmaf(gS[14 * 40 + 10 + k], wd_, a3);
        a4 = fmaf(gS[15 * 40 + 10 + k], wd_, a4);
        a5 = fmaf(gS[16 * 40 + 10 + k], wd_, a5);
      }
      hS[11 * 64 + c] = tanhf(a0); hS[12 * 64 + c] = tanhf(a1);
      hS[13 * 64 + c] = tanhf(a2); hS[14 * 64 + c] = tanhf(a3);
      hS[15 * 64 + c] = tanhf(a4); hS[16 * 64 + c] = tanhf(a5);
    } else {
      float a0 = cD, a1 = cD, a2 = cD, a3 = cD, a4 = cD;
#pragma unroll 2
      for (int k = 0; k < 30; ++k) {
        const float wd_ = WgD[(40 + k) * 64 + c];
        a0 = fmaf(gS[17 * 40 + 10 + k], wd_, a0);
        a1 = fmaf(gS[18 * 40 + 10 + k], wd_, a1);
        a2 = fmaf(gS[19 * 40 + 10 + k], wd_, a2);
        a3 = fmaf(gS[20 * 40 + 10 + k], wd_, a3);
        a4 = fmaf(gS[21 * 40 + 10 + k], wd_, a4);
      }
      hS[17 * 64 + c] = tanhf(a0); hS[18 * 64 + c] = tanhf(a1);
      hS[19 * 64 + c] = tanhf(a2); hS[20 * 64 + c] = tanhf(a3);
      hS[21 * 64 + c] = tanhf(a4);
      float aR = bgR[c];
#pragma unroll 4
      for (int k = 0; k < 40; ++k) aR = fmaf(gS[k], WgR[k * 64 + c], aR);
      hS[c] = tanhf(aR);
    }
  }
  __syncthreads();

  const float bmOc = bmO[c], bmDc = bmD[c], bmRc = bmR[c];
  float zS0 = 0.f, zS1 = 0.f, zS2 = 0.f, zS3 = 0.f, zS4 = 0.f, zS5 = 0.f;
  float aS0 = 0.f, aS1 = 0.f, aS2 = 0.f, aS3 = 0.f, aS4 = 0.f, aS5 = 0.f;

  // ---------------- 3 GRU iterations ----------------
  for (int it = 0; it < 3; ++it) {
    float nn0 = 0.f, nn1 = 0.f, nn2 = 0.f, nn3 = 0.f, nn4 = 0.f, nn5 = 0.f;
    float nRv = 0.f;

    // (a) stage n: into REGISTERS + nS (reads OLD hS cross-wave)
    if (w == 0 || w == 1) {
      const float hd0 = hS[11*64+c], hd1 = hS[12*64+c], hd2 = hS[13*64+c], hd3 = hS[14*64+c];
      const float hd4 = hS[15*64+c], hd5 = hS[16*64+c], hd6 = hS[17*64+c], hd7 = hS[18*64+c];
      const float hd8 = hS[19*64+c], hd9 = hS[20*64+c], hd10 = hS[21*64+c];
      if (w == 0) { L5A(NSO) } else { L5B(NSO) }
    } else {
      const float ho0 = hS[1*64+c], ho1 = hS[2*64+c], ho2 = hS[3*64+c], ho3 = hS[4*64+c];
      const float ho4 = hS[5*64+c], ho5 = hS[6*64+c], ho6 = hS[7*64+c], ho7 = hS[8*64+c];
      const float ho8 = hS[9*64+c], ho9 = hS[10*64+c];
      if (w == 2) { L6A(NSD) }
      else {
        L5D(NSD)
        nRv = sA2[AROB+0]*ho0 + sA2[AROB+1]*ho1 + sA2[AROB+2]*ho2 + sA2[AROB+3]*ho3
            + sA2[AROB+4]*ho4 + sA2[AROB+5]*ho5 + sA2[AROB+6]*ho6 + sA2[AROB+7]*ho7
            + sA2[AROB+8]*ho8 + sA2[AROB+9]*ho9;
        nS[c] = nRv;
      }
    }

    // (b-d) gate matvecs (reads of OLD h; own rows + hS[0] broadcast)
    if (w == 0)      { OGATE(L5A) }
    else if (w == 1) { OGATE(L5B) }
    else if (w == 2) { DGATE(L6A) }
    else {
      DGATE(L5D)
      { // gate R -> slot 5
        float azr = 0.f, arr = 0.f;
#pragma unroll 2
        for (int kb = 0; kb < 16; ++kb) {
          const float4 wz = pWzR[kb*64+c], wr = pWrR[kb*64+c];
          const float4 v = *reinterpret_cast<const float4*>(&hS[kb*4]);
          azr=fmaf(v.x,wz.x,azr); azr=fmaf(v.y,wz.y,azr); azr=fmaf(v.z,wz.z,azr); azr=fmaf(v.w,wz.w,azr);
          arr=fmaf(v.x,wr.x,arr); arr=fmaf(v.y,wr.y,arr); arr=fmaf(v.z,wr.z,arr); arr=fmaf(v.w,wr.w,arr);
        }
#pragma unroll 2
        for (int kb = 16; kb < 32; ++kb) {
          const float4 wz = pWzR[kb*64+c], wr = pWrR[kb*64+c];
          const int k4 = (kb-16)*4;
          const float t0=RLf(nRv,k4), t1=RLf(nRv,k4+1), t2=RLf(nRv,k4+2), t3=RLf(nRv,k4+3);
          azr=fmaf(t0,wz.x,azr); azr=fmaf(t1,wz.y,azr); azr=fmaf(t2,wz.z,azr); azr=fmaf(t3,wz.w,azr);
          arr=fmaf(t0,wr.x,arr); arr=fmaf(t1,wr.y,arr); arr=fmaf(t2,wr.z,arr); arr=fmaf(t3,wr.w,arr);
        }
        zS5 = sigmoidf_(azr);
        const float r5 = sigmoidf_(arr);
        gS[c] = hS[c] * r5;
        aS5 = bmRc;
#pragma unroll 2
        for (int kb = 0; kb < 16; ++kb) {
          const float4 wm = pWmR[kb*64+c];
          const float4 v = *reinterpret_cast<const float4*>(&gS[kb*4]);
          aS5=fmaf(v.x,wm.x,aS5); aS5=fmaf(v.y,wm.y,aS5); aS5=fmaf(v.z,wm.z,aS5); aS5=fmaf(v.w,wm.w,aS5);
        }
#pragma unroll 2
        for (int kb = 16; kb < 32; ++kb) {
          const float4 wm = pWmR[kb*64+c];
          const int k4 = (kb-16)*4;
          const float t0=RLf(nRv,k4), t1=RLf(nRv,k4+1), t2=RLf(nRv,k4+2), t3=RLf(nRv,k4+3);
          aS5=fmaf(t0,wm.x,aS5); aS5=fmaf(t1,wm.y,aS5); aS5=fmaf(t2,wm.z,aS5); aS5=fmaf(t3,wm.w,aS5);
        }
      }
    }

    __syncthreads();  // BARRIER A: all old-h reads complete before any h-write

    // (e) update own h rows
    if (w == 0)      { L5A(OUPD) }
    else if (w == 1) { L5B(OUPD) }
    else if (w == 2) { L6A(DUPD) }
    else {
      L5D(DUPD)
      { const float h_ = hS[c]; hS[c] = (1.f - zS5) * h_ + zS5 * tanhf(aS5); }
    }
    __syncthreads();  // BARRIER B: new h visible
  }

  // ---------------- scores (rows per wave) ----------------
  const int g = c >> 4;
  const int c1 = c & 15;
  float pR = 0.f, pO = 0.f, pD = 0.f;
  int lo, hi;
  if      (w == 0) { lo = 1;  hi = 6;  }
  else if (w == 1) { lo = 6;  hi = 11; }
  else if (w == 2) { lo = 11; hi = 17; }
  else             { lo = 17; hi = 22; }
  for (int rr = lo + g; rr < hi; rr += 4) {
    const float* W1; const float* b1; const float* W2;
    if (rr < 11) { W1 = W1O; b1 = b1O; W2 = W2O; }
    else         { W1 = W1D; b1 = b1D; W2 = W2D; }
    float a = b1[c1];
#pragma unroll 8
    for (int kk = 0; kk < 64; ++kk) {
      const int k = (kk + (g << 4)) & 63;
      a = fmaf(hS[rr * 64 + k], W1[k * 16 + c1], a);
    }
    const float t = tanhf(a) * W2[c1];
    if (rr < 11) pO += t;
    else pD += t;
  }
  if (w == 3 && g == 0) {  // row 0 (R branch)
    float a = b1R[c1];
#pragma unroll 8
    for (int kk = 0; kk < 64; ++kk) {
      a = fmaf(hS[kk], W1R[kk * 16 + c1], a);
    }
    pR = tanhf(a) * W2R[c1];
  }
#pragma unroll
  for (int off = 32; off >= 1; off >>= 1) {
    pR += __shfl_xor(pR, off, 64);
    pO += __shfl_xor(pO, off, 64);
    pD += __shfl_xor(pD, off, 64);
  }
  if (c == 0) { red[w * 4 + 0] = pR; red[w * 4 + 1] = pO; red[w * 4 + 2] = pD; }
  __syncthreads();
  if (w == 0 && c < 60) {
    const float PR = red[0] + red[4] + red[8]  + red[12];
    const float PO = red[1] + red[5] + red[9]  + red[13];
    const float PD = red[2] + red[6] + red[10] + red[14];
    out[(size_t)b * 60 + c] = PR * tp[c] + PO * tp[60 + c] + PD * tp[120 + c];
  }
}

extern "C" void kernel_launch(void* const* d_in, const int* in_sizes, int n_in,
                              void* d_out, int out_size, void* d_ws, size_t ws_size,
                              hipStream_t stream) {
  const float* X   = (const float*)d_in[0];
  const float* A   = (const float*)d_in[1];
  const float* WgR = (const float*)d_in[2];
  const float* bgR = (const float*)d_in[3];
  const float* WgO = (const float*)d_in[4];
  const float* bgO = (const float*)d_in[5];
  const float* WgD = (const float*)d_in[6];
  const float* bgD = (const float*)d_in[7];
  const float* WzR = (const float*)d_in[8];
  const float* WrR = (const float*)d_in[9];
  const float* WmR = (const float*)d_in[10];
  const float* bmR = (const float*)d_in[11];
  const float* WzO = (const float*)d_in[12];
  const float* WrO = (const float*)d_in[13];
  const float* WmO = (const float*)d_in[14];
  const float* bmO = (const float*)d_in[15];
  const float* WzD = (const float*)d_in[16];
  const float* WrD = (const float*)d_in[17];
  const float* WmD = (const float*)d_in[18];
  const float* bmD = (const float*)d_in[19];
  const float* W1R = (const float*)d_in[20];
  const float* b1R = (const float*)d_in[21];
  const float* W2R = (const float*)d_in[22];
  const float* W1O = (const float*)d_in[23];
  const float* b1O = (const float*)d_in[24];
  const float* W2O = (const float*)d_in[25];
  const float* W1D = (const float*)d_in[26];
  const float* b1D = (const float*)d_in[27];
  const float* W2D = (const float*)d_in[28];
  const float* Tmp = (const float*)d_in[29];
  const float* GK  = (const float*)d_in[30];
  const float* GRK = (const float*)d_in[31];
  const float* GB  = (const float*)d_in[32];
  const float* WO  = (const float*)d_in[33];
  const int*   IDX = (const int*)d_in[34];

  float* tp = (float*)d_ws;  // 3*60 floats in the first 1KB
  char*  ws = (char*)d_ws;
  const int B = in_sizes[0] / 880;

  hipLaunchKernelGGL(temporal_kernel, dim3(1), dim3(64), 0, stream, Tmp, GK, GRK, GB, WO, IDX, tp);
  hipLaunchKernelGGL(prep_kernel, dim3(336), dim3(64), 0, stream,
                     WzR, WrR, WmR, WzO, WrO, WmO, WzD, WrD, WmD, ws);
  hipLaunchKernelGGL(ggnn_main, dim3(B), dim3(256), 0, stream,
                     X, A, WgR, bgR, WgO, bgO, WgD, bgD,
                     bmR, bmO, bmD,
                     W1R, b1R, W2R, W1O, b1O, W2O, W1D, b1D, W2D,
                     (const char*)ws, (const float*)tp, (float*)d_out);
}

// Round 18
// 830.884 us; speedup vs baseline: 1.2574x; 1.1931x over previous
//
#include <hip/hip_runtime.h>
#include <hip/hip_bf16.h>
#include <math.h>

#define DEV __device__ __forceinline__

DEV float sigmoidf_(float x) { return 1.0f / (1.0f + __expf(-x)); }

// (slot, row) lists: slot = per-wave accumulator index, row = local gate row
#define L5A(OP) OP(0,0) OP(1,1) OP(2,2) OP(3,3) OP(4,4)
#define L5B(OP) OP(0,5) OP(1,6) OP(2,7) OP(3,8) OP(4,9)
#define L6A(OP) OP(0,0) OP(1,1) OP(2,2) OP(3,3) OP(4,4) OP(5,5)
#define L5D(OP) OP(0,6) OP(1,7) OP(2,8) OP(3,9) OP(4,10)

// Compact A staging (240 used entries of the 22x22 matrix)
#define AROB 0
#define AORB 16
#define AODB 32
#define ADOB 144
#define ANUM 256

DEV float gstep(float x, float h, const float* k, const float* rk, const float* bb) {
  const float z  = sigmoidf_(fmaf(x, k[0], bb[0]) + fmaf(h, rk[0], bb[3]));
  const float r  = sigmoidf_(fmaf(x, k[1], bb[1]) + fmaf(h, rk[1], bb[4]));
  const float hh = tanhf(fmaf(x, k[2], bb[2]) + r * fmaf(h, rk[2], bb[5]));
  return z * h + (1.f - z) * hh;
}

__global__ void __launch_bounds__(64, 1)
temporal_kernel(const float* __restrict__ T, const float* __restrict__ GK,
                const float* __restrict__ GRK, const float* __restrict__ GB,
                const float* __restrict__ WO, const int* __restrict__ IDX,
                float* __restrict__ tp) {
  const int i = threadIdx.x;
  __shared__ float fb[3][75];
  __shared__ float gg[3][75];
  if (i < 3) {
    float k0[3], k1[3], rk0[3], rk1[3];
#pragma unroll
    for (int q = 0; q < 3; ++q) {
      k0[q]  = GK[i * 6 + q];      k1[q]  = GK[i * 6 + 3 + q];
      rk0[q] = GRK[i * 6 + q];     rk1[q] = GRK[i * 6 + 3 + q];
    }
    const float* B0 = GB + i * 12;
    const float* B1 = GB + i * 12 + 6;
    float h = 0.f;
    for (int s = 0; s < 75; ++s) { h = gstep(T[i * 75 + s], h, k0, rk0, B0); fb[i][s] = h; }
    h = 0.f;
    for (int s = 0; s < 75; ++s) { h = gstep(fb[i][74 - s], h, k1, rk1, B1); gg[i][s] = h; }
    const float wo = WO[i];
    float mx = -1e30f;
    for (int s = 0; s < 75; ++s) mx = fmaxf(mx, gg[i][s] * wo);
    float sum = 0.f;
    for (int s = 0; s < 75; ++s) { const float e = __expf(gg[i][s] * wo - mx); fb[i][s] = e; sum += e; }
    const float inv = 1.f / sum;
    for (int j = 0; j < 60; ++j) tp[i * 60 + j] = fb[i][IDX[j]] * inv;
  }
}

// Weight repack (proven R13): lane c's 4 consecutive k-values as one dwordx4.
// ws layout (1KB/k4-block): ZR[0..31] RR[32..63] MR[64..95] ZO[96..143]
// RO[144..191] MO[192..239] ZD[240..271] RD[272..303] MD[304..335]
__global__ void __launch_bounds__(64, 1) prep_kernel(
    const float* __restrict__ WzR, const float* __restrict__ WrR, const float* __restrict__ WmR,
    const float* __restrict__ WzO, const float* __restrict__ WrO, const float* __restrict__ WmO,
    const float* __restrict__ WzD, const float* __restrict__ WrD, const float* __restrict__ WmD,
    char* __restrict__ ws) {
  const int fi = blockIdx.x;
  const int c = threadIdx.x;
  const float* W; int base;
  if      (fi <  32) { W = WzR; base = 0;   }
  else if (fi <  64) { W = WrR; base = 32;  }
  else if (fi <  96) { W = WmR; base = 64;  }
  else if (fi < 144) { W = WzO; base = 96;  }
  else if (fi < 192) { W = WrO; base = 144; }
  else if (fi < 240) { W = WmO; base = 192; }
  else if (fi < 272) { W = WzD; base = 240; }
  else if (fi < 304) { W = WrD; base = 272; }
  else               { W = WmD; base = 304; }
  const int kb = fi - base;
  float4 v;
  v.x = W[(kb * 4 + 0) * 64 + c];
  v.y = W[(kb * 4 + 1) * 64 + c];
  v.z = W[(kb * 4 + 2) * 64 + c];
  v.w = W[(kb * 4 + 3) * 64 + c];
  *(float4*)(ws + 1024 + (size_t)fi * 1024 + c * 16) = v;
}

// ---- per-row macro bodies (s=slot, i=local row); hc = old-h buffer,
// hn = new-h buffer (ping-pong; ONE barrier per iteration) ----
#define ZRDECL(s,i) float az##s = 0.f, ar##s = 0.f;
#define AORD(s,i)  const float aor##s = sA2[AORB + (i)];
#define OS0(s,i) { const float4 v = *reinterpret_cast<const float4*>(&hc[(1+(i))*64 + kb*4]); \
  az##s=fmaf(v.x,wz.x,az##s); az##s=fmaf(v.y,wz.y,az##s); az##s=fmaf(v.z,wz.z,az##s); az##s=fmaf(v.w,wz.w,az##s); \
  ar##s=fmaf(v.x,wr.x,ar##s); ar##s=fmaf(v.y,wr.y,ar##s); ar##s=fmaf(v.z,wr.z,ar##s); ar##s=fmaf(v.w,wr.w,ar##s); }
#define OS1(s,i) { az##s=fmaf(aor##s,uz.x,az##s); az##s=fmaf(aor##s,uz.y,az##s); \
  az##s=fmaf(aor##s,uz.z,az##s); az##s=fmaf(aor##s,uz.w,az##s); \
  ar##s=fmaf(aor##s,ur.x,ar##s); ar##s=fmaf(aor##s,ur.y,ar##s); \
  ar##s=fmaf(aor##s,ur.z,ar##s); ar##s=fmaf(aor##s,ur.w,ar##s); }
#define OS2(s,i) { const float4 v = *reinterpret_cast<const float4*>(&nS[(1+(i))*64 + (kb-32)*4]); \
  az##s=fmaf(v.x,wz.x,az##s); az##s=fmaf(v.y,wz.y,az##s); az##s=fmaf(v.z,wz.z,az##s); az##s=fmaf(v.w,wz.w,az##s); \
  ar##s=fmaf(v.x,wr.x,ar##s); ar##s=fmaf(v.y,wr.y,ar##s); ar##s=fmaf(v.z,wr.z,ar##s); ar##s=fmaf(v.w,wr.w,ar##s); }
#define OSIG(s,i) zS##s = sigmoidf_(az##s); const float rr##s = sigmoidf_(ar##s);
#define OGST(s,i) gS[(1+(i))*64+c] = hc[(1+(i))*64+c] * rr##s;
#define OAMD(s,i) aS##s = bmOc;
#define OM0(s,i) { const float4 v = *reinterpret_cast<const float4*>(&gS[(1+(i))*64 + kb*4]); \
  aS##s=fmaf(v.x,wm.x,aS##s); aS##s=fmaf(v.y,wm.y,aS##s); aS##s=fmaf(v.z,wm.z,aS##s); aS##s=fmaf(v.w,wm.w,aS##s); }
#define OM1(s,i) { aS##s=fmaf(aor##s,um.x,aS##s); aS##s=fmaf(aor##s,um.y,aS##s); \
  aS##s=fmaf(aor##s,um.z,aS##s); aS##s=fmaf(aor##s,um.w,aS##s); }
#define OM2(s,i) { const float4 v = *reinterpret_cast<const float4*>(&nS[(1+(i))*64 + (kb-32)*4]); \
  aS##s=fmaf(v.x,wm.x,aS##s); aS##s=fmaf(v.y,wm.y,aS##s); aS##s=fmaf(v.z,wm.z,aS##s); aS##s=fmaf(v.w,wm.w,aS##s); }

#define DS0(s,i) { const float4 v = *reinterpret_cast<const float4*>(&hc[(11+(i))*64 + kb*4]); \
  az##s=fmaf(v.x,wz.x,az##s); az##s=fmaf(v.y,wz.y,az##s); az##s=fmaf(v.z,wz.z,az##s); az##s=fmaf(v.w,wz.w,az##s); \
  ar##s=fmaf(v.x,wr.x,ar##s); ar##s=fmaf(v.y,wr.y,ar##s); ar##s=fmaf(v.z,wr.z,ar##s); ar##s=fmaf(v.w,wr.w,ar##s); }
#define DS1(s,i) { const float4 v = *reinterpret_cast<const float4*>(&nS[(11+(i))*64 + (kb-16)*4]); \
  az##s=fmaf(v.x,wz.x,az##s); az##s=fmaf(v.y,wz.y,az##s); az##s=fmaf(v.z,wz.z,az##s); az##s=fmaf(v.w,wz.w,az##s); \
  ar##s=fmaf(v.x,wr.x,ar##s); ar##s=fmaf(v.y,wr.y,ar##s); ar##s=fmaf(v.z,wr.z,ar##s); ar##s=fmaf(v.w,wr.w,ar##s); }
#define DSIG(s,i) zS##s = sigmoidf_(az##s); const float rr##s = sigmoidf_(ar##s);
#define DGST(s,i) gS[(11+(i))*64+c] = hc[(11+(i))*64+c] * rr##s;
#define DAMD(s,i) aS##s = bmDc;
#define DM0(s,i) { const float4 v = *reinterpret_cast<const float4*>(&gS[(11+(i))*64 + kb*4]); \
  aS##s=fmaf(v.x,wm.x,aS##s); aS##s=fmaf(v.y,wm.y,aS##s); aS##s=fmaf(v.z,wm.z,aS##s); aS##s=fmaf(v.w,wm.w,aS##s); }
#define DM1(s,i) { const float4 v = *reinterpret_cast<const float4*>(&nS[(11+(i))*64 + (kb-16)*4]); \
  aS##s=fmaf(v.x,wm.x,aS##s); aS##s=fmaf(v.y,wm.y,aS##s); aS##s=fmaf(v.z,wm.z,aS##s); aS##s=fmaf(v.w,wm.w,aS##s); }

#define OGATE(LIST) { \
  LIST(ZRDECL) LIST(AORD) \
  _Pragma("unroll 2") for (int kb = 0; kb < 16; ++kb) { \
    const float4 wz = pWzO[kb*64+c], wr = pWrO[kb*64+c]; LIST(OS0) } \
  _Pragma("unroll 2") for (int kb = 16; kb < 32; ++kb) { \
    const float4 wz = pWzO[kb*64+c], wr = pWrO[kb*64+c]; \
    const float4 h0 = *reinterpret_cast<const float4*>(&hc[(kb-16)*4]); \
    float4 uz, ur; \
    uz.x=h0.x*wz.x; uz.y=h0.y*wz.y; uz.z=h0.z*wz.z; uz.w=h0.w*wz.w; \
    ur.x=h0.x*wr.x; ur.y=h0.y*wr.y; ur.z=h0.z*wr.z; ur.w=h0.w*wr.w; \
    LIST(OS1) } \
  _Pragma("unroll 2") for (int kb = 32; kb < 48; ++kb) { \
    const float4 wz = pWzO[kb*64+c], wr = pWrO[kb*64+c]; LIST(OS2) } \
  LIST(OSIG) LIST(OGST) LIST(OAMD) \
  _Pragma("unroll 2") for (int kb = 0; kb < 16; ++kb) { \
    const float4 wm = pWmO[kb*64+c]; LIST(OM0) } \
  _Pragma("unroll 2") for (int kb = 16; kb < 32; ++kb) { \
    const float4 wm = pWmO[kb*64+c]; \
    const float4 h0 = *reinterpret_cast<const float4*>(&hc[(kb-16)*4]); \
    float4 um; um.x=h0.x*wm.x; um.y=h0.y*wm.y; um.z=h0.z*wm.z; um.w=h0.w*wm.w; \
    LIST(OM1) } \
  _Pragma("unroll 2") for (int kb = 32; kb < 48; ++kb) { \
    const float4 wm = pWmO[kb*64+c]; LIST(OM2) } }

#define DGATE(LIST) { \
  LIST(ZRDECL) \
  _Pragma("unroll 2") for (int kb = 0; kb < 16; ++kb) { \
    const float4 wz = pWzD[kb*64+c], wr = pWrD[kb*64+c]; LIST(DS0) } \
  _Pragma("unroll 2") for (int kb = 16; kb < 32; ++kb) { \
    const float4 wz = pWzD[kb*64+c], wr = pWrD[kb*64+c]; LIST(DS1) } \
  LIST(DSIG) LIST(DGST) LIST(DAMD) \
  _Pragma("unroll 2") for (int kb = 0; kb < 16; ++kb) { \
    const float4 wm = pWmD[kb*64+c]; LIST(DM0) } \
  _Pragma("unroll 2") for (int kb = 16; kb < 32; ++kb) { \
    const float4 wm = pWmD[kb*64+c]; LIST(DM1) } }

#define OUPD(s,i) { const float h_ = hc[(1+(i))*64+c]; \
  hn[(1+(i))*64+c] = (1.f - zS##s)*h_ + zS##s*tanhf(aS##s); }
#define DUPD(s,i) { const float h_ = hc[(11+(i))*64+c]; \
  hn[(11+(i))*64+c] = (1.f - zS##s)*h_ + zS##s*tanhf(aS##s); }

#define NSO(s,i) nS[(1+(i))*64+c] = \
  sA2[AODB+(i)*11+0]*hd0 + sA2[AODB+(i)*11+1]*hd1 + sA2[AODB+(i)*11+2]*hd2 + sA2[AODB+(i)*11+3]*hd3 \
+ sA2[AODB+(i)*11+4]*hd4 + sA2[AODB+(i)*11+5]*hd5 + sA2[AODB+(i)*11+6]*hd6 + sA2[AODB+(i)*11+7]*hd7 \
+ sA2[AODB+(i)*11+8]*hd8 + sA2[AODB+(i)*11+9]*hd9 + sA2[AODB+(i)*11+10]*hd10;
#define NSD(s,i) nS[(11+(i))*64+c] = \
  sA2[ADOB+(i)*10+0]*ho0 + sA2[ADOB+(i)*10+1]*ho1 + sA2[ADOB+(i)*10+2]*ho2 + sA2[ADOB+(i)*10+3]*ho3 \
+ sA2[ADOB+(i)*10+4]*ho4 + sA2[ADOB+(i)*10+5]*ho5 + sA2[ADOB+(i)*10+6]*ho6 + sA2[ADOB+(i)*10+7]*ho7 \
+ sA2[ADOB+(i)*10+8]*ho8 + sA2[ADOB+(i)*10+9]*ho9;

// 256 threads = 4 waves on ONE batch element; h state PING-PONGED in LDS
// (hS0/hS1) so each GRU iteration needs ONE barrier (R15 needed two: WAR
// old-h-read vs h-write + RAW new-h visibility; the swap folds both into
// the single end-of-iteration barrier). Rows per wave as R15.
__global__ void __launch_bounds__(256) ggnn_main(
    const float* __restrict__ X, const float* __restrict__ A,
    const float* __restrict__ WgR, const float* __restrict__ bgR,
    const float* __restrict__ WgO, const float* __restrict__ bgO,
    const float* __restrict__ WgD, const float* __restrict__ bgD,
    const float* __restrict__ bmR, const float* __restrict__ bmO, const float* __restrict__ bmD,
    const float* __restrict__ W1R, const float* __restrict__ b1R, const float* __restrict__ W2R,
    const float* __restrict__ W1O, const float* __restrict__ b1O, const float* __restrict__ W2O,
    const float* __restrict__ W1D, const float* __restrict__ b1D, const float* __restrict__ W2D,
    const char* __restrict__ ws, const float* __restrict__ tp,
    float* __restrict__ out) {
  const int b = blockIdx.x;
  const int w = threadIdx.x >> 6;
  const int c = threadIdx.x & 63;
  const int tid = threadIdx.x;

  __shared__ __align__(16) float hS0[22 * 64];  // h ping
  __shared__ __align__(16) float hS1[22 * 64];  // h pong
  __shared__ __align__(16) float nS[22 * 64];   // staged n (wave-private rows)
  __shared__ __align__(16) float gS[22 * 64];   // h*r staging; X stage at init
  __shared__ float sA2[ANUM];
  __shared__ float red[16];

  const float4* pk = (const float4*)(ws + 1024);
  const float4* pWzR = pk + 0   * 64;
  const float4* pWrR = pk + 32  * 64;
  const float4* pWmR = pk + 64  * 64;
  const float4* pWzO = pk + 96  * 64;
  const float4* pWrO = pk + 144 * 64;
  const float4* pWmO = pk + 192 * 64;
  const float4* pWzD = pk + 240 * 64;
  const float4* pWrD = pk + 272 * 64;
  const float4* pWmD = pk + 304 * 64;

  const float* Xb = X + (size_t)b * 880;
  const float* Ab = A + (size_t)b * 484;
  for (int t = tid; t < 880; t += 256) gS[t] = Xb[t];
  if (tid < 10) {
    sA2[AROB + tid] = Ab[1 + tid];
    sA2[AORB + tid] = Ab[(1 + tid) * 22];
  }
  for (int t = tid; t < 110; t += 256) {
    const int i = t / 11, j = t - i * 11;
    sA2[AODB + t] = Ab[(1 + i) * 22 + 11 + j];
  }
  for (int t = tid; t < 110; t += 256) {
    const int i = t / 10, j = t - i * 10;
    sA2[ADOB + t] = Ab[(11 + i) * 22 + 1 + j];
  }
  __syncthreads();

  // ---------------- phase 0: h = tanh(Xg @ Wg + bg) -> hS0 ----------------
  {
    float* hw = hS0;
    if (w == 0 || w == 1) {
      float cO = bgO[c];
#pragma unroll 4
      for (int k = 0; k < 40; ++k) cO = fmaf(gS[k], WgO[k * 64 + c], cO);
      float a0 = cO, a1 = cO, a2 = cO, a3 = cO, a4 = cO;
      const int r0 = (w == 0) ? 1 : 6;
#pragma unroll 2
      for (int k = 0; k < 30; ++k) {
        const float wo_ = WgO[(40 + k) * 64 + c];
        a0 = fmaf(gS[(r0 + 0) * 40 + 10 + k], wo_, a0);
        a1 = fmaf(gS[(r0 + 1) * 40 + 10 + k], wo_, a1);
        a2 = fmaf(gS[(r0 + 2) * 40 + 10 + k], wo_, a2);
        a3 = fmaf(gS[(r0 + 3) * 40 + 10 + k], wo_, a3);
        a4 = fmaf(gS[(r0 + 4) * 40 + 10 + k], wo_, a4);
      }
      hw[(r0 + 0) * 64 + c] = tanhf(a0);
      hw[(r0 + 1) * 64 + c] = tanhf(a1);
      hw[(r0 + 2) * 64 + c] = tanhf(a2);
      hw[(r0 + 3) * 64 + c] = tanhf(a3);
      hw[(r0 + 4) * 64 + c] = tanhf(a4);
    } else {
      float cD = bgD[c];
#pragma unroll 4
      for (int k = 0; k < 40; ++k) cD = fmaf(gS[k], WgD[k * 64 + c], cD);
      if (w == 2) {
        float a0 = cD, a1 = cD, a2 = cD, a3 = cD, a4 = cD, a5 = cD;
#pragma unroll 2
        for (int k = 0; k < 30; ++k) {
          const float wd_ = WgD[(40 + k) * 64 + c];
          a0 = fmaf(gS[11 * 40 + 10 + k], wd_, a0);
          a1 = fmaf(gS[12 * 40 + 10 + k], wd_, a1);
          a2 = fmaf(gS[13 * 40 + 10 + k], wd_, a2);
          a3 = fmaf(gS[14 * 40 + 10 + k], wd_, a3);
          a4 = fmaf(gS[15 * 40 + 10 + k], wd_, a4);
          a5 = fmaf(gS[16 * 40 + 10 + k], wd_, a5);
        }
        hw[11 * 64 + c] = tanhf(a0); hw[12 * 64 + c] = tanhf(a1);
        hw[13 * 64 + c] = tanhf(a2); hw[14 * 64 + c] = tanhf(a3);
        hw[15 * 64 + c] = tanhf(a4); hw[16 * 64 + c] = tanhf(a5);
      } else {
        float a0 = cD, a1 = cD, a2 = cD, a3 = cD, a4 = cD;
#pragma unroll 2
        for (int k = 0; k < 30; ++k) {
          const float wd_ = WgD[(40 + k) * 64 + c];
          a0 = fmaf(gS[17 * 40 + 10 + k], wd_, a0);
          a1 = fmaf(gS[18 * 40 + 10 + k], wd_, a1);
          a2 = fmaf(gS[19 * 40 + 10 + k], wd_, a2);
          a3 = fmaf(gS[20 * 40 + 10 + k], wd_, a3);
          a4 = fmaf(gS[21 * 40 + 10 + k], wd_, a4);
        }
        hw[17 * 64 + c] = tanhf(a0); hw[18 * 64 + c] = tanhf(a1);
        hw[19 * 64 + c] = tanhf(a2); hw[20 * 64 + c] = tanhf(a3);
        hw[21 * 64 + c] = tanhf(a4);
        float aR = bgR[c];
#pragma unroll 4
        for (int k = 0; k < 40; ++k) aR = fmaf(gS[k], WgR[k * 64 + c], aR);
        hw[c] = tanhf(aR);
      }
    }
  }
  __syncthreads();

  const float bmOc = bmO[c], bmDc = bmD[c], bmRc = bmR[c];
  float zS0 = 0.f, zS1 = 0.f, zS2 = 0.f, zS3 = 0.f, zS4 = 0.f, zS5 = 0.f;
  float aS0 = 0.f, aS1 = 0.f, aS2 = 0.f, aS3 = 0.f, aS4 = 0.f, aS5 = 0.f;

  // ---------------- 3 GRU iterations (ONE barrier each) ----------------
  for (int it = 0; it < 3; ++it) {
    float* hc = (it & 1) ? hS1 : hS0;  // read old h
    float* hn = (it & 1) ? hS0 : hS1;  // write new h

    // (a) stage n (reads OLD hc cross-wave; writes own nS rows)
    if (w == 0 || w == 1) {
      const float hd0 = hc[11*64+c], hd1 = hc[12*64+c], hd2 = hc[13*64+c], hd3 = hc[14*64+c];
      const float hd4 = hc[15*64+c], hd5 = hc[16*64+c], hd6 = hc[17*64+c], hd7 = hc[18*64+c];
      const float hd8 = hc[19*64+c], hd9 = hc[20*64+c], hd10 = hc[21*64+c];
      if (w == 0) { L5A(NSO) } else { L5B(NSO) }
    } else {
      const float ho0 = hc[1*64+c], ho1 = hc[2*64+c], ho2 = hc[3*64+c], ho3 = hc[4*64+c];
      const float ho4 = hc[5*64+c], ho5 = hc[6*64+c], ho6 = hc[7*64+c], ho7 = hc[8*64+c];
      const float ho8 = hc[9*64+c], ho9 = hc[10*64+c];
      if (w == 2) { L6A(NSD) }
      else {
        L5D(NSD)
        nS[c] = sA2[AROB+0]*ho0 + sA2[AROB+1]*ho1 + sA2[AROB+2]*ho2 + sA2[AROB+3]*ho3
              + sA2[AROB+4]*ho4 + sA2[AROB+5]*ho5 + sA2[AROB+6]*ho6 + sA2[AROB+7]*ho7
              + sA2[AROB+8]*ho8 + sA2[AROB+9]*ho9;
      }
    }

    // (b-d) gate matvecs (read OLD hc) + (e) update into hn
    if (w == 0)      { OGATE(L5A) L5A(OUPD) }
    else if (w == 1) { OGATE(L5B) L5B(OUPD) }
    else if (w == 2) { DGATE(L6A) L6A(DUPD) }
    else {
      DGATE(L5D)
      { // gate R -> slot 5
        float azr = 0.f, arr = 0.f;
#pragma unroll 2
        for (int kb = 0; kb < 16; ++kb) {
          const float4 wz = pWzR[kb*64+c], wr = pWrR[kb*64+c];
          const float4 v = *reinterpret_cast<const float4*>(&hc[kb*4]);
          azr=fmaf(v.x,wz.x,azr); azr=fmaf(v.y,wz.y,azr); azr=fmaf(v.z,wz.z,azr); azr=fmaf(v.w,wz.w,azr);
          arr=fmaf(v.x,wr.x,arr); arr=fmaf(v.y,wr.y,arr); arr=fmaf(v.z,wr.z,arr); arr=fmaf(v.w,wr.w,arr);
        }
#pragma unroll 2
        for (int kb = 16; kb < 32; ++kb) {
          const float4 wz = pWzR[kb*64+c], wr = pWrR[kb*64+c];
          const float4 v = *reinterpret_cast<const float4*>(&nS[(kb-16)*4]);
          azr=fmaf(v.x,wz.x,azr); azr=fmaf(v.y,wz.y,azr); azr=fmaf(v.z,wz.z,azr); azr=fmaf(v.w,wz.w,azr);
          arr=fmaf(v.x,wr.x,arr); arr=fmaf(v.y,wr.y,arr); arr=fmaf(v.z,wr.z,arr); arr=fmaf(v.w,wr.w,arr);
        }
        zS5 = sigmoidf_(azr);
        const float r5 = sigmoidf_(arr);
        gS[c] = hc[c] * r5;
        aS5 = bmRc;
#pragma unroll 2
        for (int kb = 0; kb < 16; ++kb) {
          const float4 wm = pWmR[kb*64+c];
          const float4 v = *reinterpret_cast<const float4*>(&gS[kb*4]);
          aS5=fmaf(v.x,wm.x,aS5); aS5=fmaf(v.y,wm.y,aS5); aS5=fmaf(v.z,wm.z,aS5); aS5=fmaf(v.w,wm.w,aS5);
        }
#pragma unroll 2
        for (int kb = 16; kb < 32; ++kb) {
          const float4 wm = pWmR[kb*64+c];
          const float4 v = *reinterpret_cast<const float4*>(&nS[(kb-16)*4]);
          aS5=fmaf(v.x,wm.x,aS5); aS5=fmaf(v.y,wm.y,aS5); aS5=fmaf(v.z,wm.z,aS5); aS5=fmaf(v.w,wm.w,aS5);
        }
      }
      L5D(DUPD)
      { const float h_ = hc[c]; hn[c] = (1.f - zS5) * h_ + zS5 * tanhf(aS5); }
    }
    __syncthreads();  // single barrier: new-h visible AND hc free for rewrite
  }

  // final h is in hS1 (it=2 wrote hn=hS1)
  float* hF = hS1;

  // ---------------- scores (rows per wave) ----------------
  const int g = c >> 4;
  const int c1 = c & 15;
  float pR = 0.f, pO = 0.f, pD = 0.f;
  int lo, hi;
  if      (w == 0) { lo = 1;  hi = 6;  }
  else if (w == 1) { lo = 6;  hi = 11; }
  else if (w == 2) { lo = 11; hi = 17; }
  else             { lo = 17; hi = 22; }
  for (int rr = lo + g; rr < hi; rr += 4) {
    const float* W1; const float* b1; const float* W2;
    if (rr < 11) { W1 = W1O; b1 = b1O; W2 = W2O; }
    else         { W1 = W1D; b1 = b1D; W2 = W2D; }
    float a = b1[c1];
#pragma unroll 8
    for (int kk = 0; kk < 64; ++kk) {
      const int k = (kk + (g << 4)) & 63;
      a = fmaf(hF[rr * 64 + k], W1[k * 16 + c1], a);
    }
    const float t = tanhf(a) * W2[c1];
    if (rr < 11) pO += t;
    else pD += t;
  }
  if (w == 3 && g == 0) {  // row 0 (R branch)
    float a = b1R[c1];
#pragma unroll 8
    for (int kk = 0; kk < 64; ++kk) {
      a = fmaf(hF[kk], W1R[kk * 16 + c1], a);
    }
    pR = tanhf(a) * W2R[c1];
  }
#pragma unroll
  for (int off = 32; off >= 1; off >>= 1) {
    pR += __shfl_xor(pR, off, 64);
    pO += __shfl_xor(pO, off, 64);
    pD += __shfl_xor(pD, off, 64);
  }
  if (c == 0) { red[w * 4 + 0] = pR; red[w * 4 + 1] = pO; red[w * 4 + 2] = pD; }
  __syncthreads();
  if (w == 0 && c < 60) {
    const float PR = red[0] + red[4] + red[8]  + red[12];
    const float PO = red[1] + red[5] + red[9]  + red[13];
    const float PD = red[2] + red[6] + red[10] + red[14];
    out[(size_t)b * 60 + c] = PR * tp[c] + PO * tp[60 + c] + PD * tp[120 + c];
  }
}

extern "C" void kernel_launch(void* const* d_in, const int* in_sizes, int n_in,
                              void* d_out, int out_size, void* d_ws, size_t ws_size,
                              hipStream_t stream) {
  const float* X   = (const float*)d_in[0];
  const float* A   = (const float*)d_in[1];
  const float* WgR = (const float*)d_in[2];
  const float* bgR = (const float*)d_in[3];
  const float* WgO = (const float*)d_in[4];
  const float* bgO = (const float*)d_in[5];
  const float* WgD = (const float*)d_in[6];
  const float* bgD = (const float*)d_in[7];
  const float* WzR = (const float*)d_in[8];
  const float* WrR = (const float*)d_in[9];
  const float* WmR = (const float*)d_in[10];
  const float* bmR = (const float*)d_in[11];
  const float* WzO = (const float*)d_in[12];
  const float* WrO = (const float*)d_in[13];
  const float* WmO = (const float*)d_in[14];
  const float* bmO = (const float*)d_in[15];
  const float* WzD = (const float*)d_in[16];
  const float* WrD = (const float*)d_in[17];
  const float* WmD = (const float*)d_in[18];
  const float* bmD = (const float*)d_in[19];
  const float* W1R = (const float*)d_in[20];
  const float* b1R = (const float*)d_in[21];
  const float* W2R = (const float*)d_in[22];
  const float* W1O = (const float*)d_in[23];
  const float* b1O = (const float*)d_in[24];
  const float* W2O = (const float*)d_in[25];
  const float* W1D = (const float*)d_in[26];
  const float* b1D = (const float*)d_in[27];
  const float* W2D = (const float*)d_in[28];
  const float* Tmp = (const float*)d_in[29];
  const float* GK  = (const float*)d_in[30];
  const float* GRK = (const float*)d_in[31];
  const float* GB  = (const float*)d_in[32];
  const float* WO  = (const float*)d_in[33];
  const int*   IDX = (const int*)d_in[34];

  float* tp = (float*)d_ws;  // 3*60 floats in the first 1KB
  char*  ws = (char*)d_ws;
  const int B = in_sizes[0] / 880;

  hipLaunchKernelGGL(temporal_kernel, dim3(1), dim3(64), 0, stream, Tmp, GK, GRK, GB, WO, IDX, tp);
  hipLaunchKernelGGL(prep_kernel, dim3(336), dim3(64), 0, stream,
                     WzR, WrR, WmR, WzO, WrO, WmO, WzD, WrD, WmD, ws);
  hipLaunchKernelGGL(ggnn_main, dim3(B), dim3(256), 0, stream,
                     X, A, WgR, bgR, WgO, bgO, WgD, bgD,
                     bmR, bmO, bmD,
                     W1R, b1R, W2R, W1O, b1O, W2O, W1D, b1D, W2D,
                     (const char*)ws, (const float*)tp, (float*)d_out);
}

// Round 19
// 805.867 us; speedup vs baseline: 1.2965x; 1.0310x over previous
//
#include <hip/hip_runtime.h>
#include <hip/hip_bf16.h>
#include <math.h>

#define DEV __device__ __forceinline__

typedef __attribute__((ext_vector_type(2))) float f32x2;

DEV float sigmoidf_(float x) { return 1.0f / (1.0f + __expf(-x)); }
DEV f32x2 mk2(float x, float y) { f32x2 r; r.x = x; r.y = y; return r; }
// packed fp32 FMA: lowers to v_pk_fma_f32 (VOP3P) on gfx90a+/gfx950 — 2 FMAs
// per lane per instruction. The R15/R18 kernels are VALU-issue-bound
// (VALUBusy 74% = 615us of 830us); this halves the matvec FMA stream.
DEV f32x2 PKF(f32x2 a, f32x2 b, f32x2 c) { return __builtin_elementwise_fma(a, b, c); }

// (slot, row) lists: slot = per-wave accumulator index, row = local gate row
#define L5A(OP) OP(0,0) OP(1,1) OP(2,2) OP(3,3) OP(4,4)
#define L5B(OP) OP(0,5) OP(1,6) OP(2,7) OP(3,8) OP(4,9)
#define L6A(OP) OP(0,0) OP(1,1) OP(2,2) OP(3,3) OP(4,4) OP(5,5)
#define L5D(OP) OP(0,6) OP(1,7) OP(2,8) OP(3,9) OP(4,10)

// Compact A staging (240 used entries of the 22x22 matrix)
#define AROB 0
#define AORB 16
#define AODB 32
#define ADOB 144
#define ANUM 256

DEV float gstep(float x, float h, const float* k, const float* rk, const float* bb) {
  const float z  = sigmoidf_(fmaf(x, k[0], bb[0]) + fmaf(h, rk[0], bb[3]));
  const float r  = sigmoidf_(fmaf(x, k[1], bb[1]) + fmaf(h, rk[1], bb[4]));
  const float hh = tanhf(fmaf(x, k[2], bb[2]) + r * fmaf(h, rk[2], bb[5]));
  return z * h + (1.f - z) * hh;
}

__global__ void __launch_bounds__(64, 1)
temporal_kernel(const float* __restrict__ T, const float* __restrict__ GK,
                const float* __restrict__ GRK, const float* __restrict__ GB,
                const float* __restrict__ WO, const int* __restrict__ IDX,
                float* __restrict__ tp) {
  const int i = threadIdx.x;
  __shared__ float fb[3][75];
  __shared__ float gg[3][75];
  if (i < 3) {
    float k0[3], k1[3], rk0[3], rk1[3];
#pragma unroll
    for (int q = 0; q < 3; ++q) {
      k0[q]  = GK[i * 6 + q];      k1[q]  = GK[i * 6 + 3 + q];
      rk0[q] = GRK[i * 6 + q];     rk1[q] = GRK[i * 6 + 3 + q];
    }
    const float* B0 = GB + i * 12;
    const float* B1 = GB + i * 12 + 6;
    float h = 0.f;
    for (int s = 0; s < 75; ++s) { h = gstep(T[i * 75 + s], h, k0, rk0, B0); fb[i][s] = h; }
    h = 0.f;
    for (int s = 0; s < 75; ++s) { h = gstep(fb[i][74 - s], h, k1, rk1, B1); gg[i][s] = h; }
    const float wo = WO[i];
    float mx = -1e30f;
    for (int s = 0; s < 75; ++s) mx = fmaxf(mx, gg[i][s] * wo);
    float sum = 0.f;
    for (int s = 0; s < 75; ++s) { const float e = __expf(gg[i][s] * wo - mx); fb[i][s] = e; sum += e; }
    const float inv = 1.f / sum;
    for (int j = 0; j < 60; ++j) tp[i * 60 + j] = fb[i][IDX[j]] * inv;
  }
}

// Weight repack (proven R13): lane c's 4 consecutive k-values as one dwordx4.
// ws layout (1KB/k4-block): ZR[0..31] RR[32..63] MR[64..95] ZO[96..143]
// RO[144..191] MO[192..239] ZD[240..271] RD[272..303] MD[304..335]
__global__ void __launch_bounds__(64, 1) prep_kernel(
    const float* __restrict__ WzR, const float* __restrict__ WrR, const float* __restrict__ WmR,
    const float* __restrict__ WzO, const float* __restrict__ WrO, const float* __restrict__ WmO,
    const float* __restrict__ WzD, const float* __restrict__ WrD, const float* __restrict__ WmD,
    char* __restrict__ ws) {
  const int fi = blockIdx.x;
  const int c = threadIdx.x;
  const float* W; int base;
  if      (fi <  32) { W = WzR; base = 0;   }
  else if (fi <  64) { W = WrR; base = 32;  }
  else if (fi <  96) { W = WmR; base = 64;  }
  else if (fi < 144) { W = WzO; base = 96;  }
  else if (fi < 192) { W = WrO; base = 144; }
  else if (fi < 240) { W = WmO; base = 192; }
  else if (fi < 272) { W = WzD; base = 240; }
  else if (fi < 304) { W = WrD; base = 272; }
  else               { W = WmD; base = 304; }
  const int kb = fi - base;
  float4 v;
  v.x = W[(kb * 4 + 0) * 64 + c];
  v.y = W[(kb * 4 + 1) * 64 + c];
  v.z = W[(kb * 4 + 2) * 64 + c];
  v.w = W[(kb * 4 + 3) * 64 + c];
  *(float4*)(ws + 1024 + (size_t)fi * 1024 + c * 16) = v;
}

// ---- per-row macro bodies (s=slot, i=local row); hc = old-h, hn = new-h
// (ping-pong, ONE barrier/iter). Accumulators are f32x2 (packed fp32). ----
#define ZRDECL(s,i) f32x2 az##s = mk2(0.f,0.f), ar##s = mk2(0.f,0.f);
#define AORD(s,i)  const f32x2 aor2##s = mk2(sA2[AORB + (i)], sA2[AORB + (i)]);
#define OS0(s,i) { const float4 v = *reinterpret_cast<const float4*>(&hc[(1+(i))*64 + kb*4]); \
  az##s = PKF(mk2(v.x,v.y), wz01, az##s); az##s = PKF(mk2(v.z,v.w), wz23, az##s); \
  ar##s = PKF(mk2(v.x,v.y), wr01, ar##s); ar##s = PKF(mk2(v.z,v.w), wr23, ar##s); }
#define OS1(s,i) { az##s = PKF(aor2##s, uz01, az##s); az##s = PKF(aor2##s, uz23, az##s); \
  ar##s = PKF(aor2##s, ur01, ar##s); ar##s = PKF(aor2##s, ur23, ar##s); }
#define OS2(s,i) { const float4 v = *reinterpret_cast<const float4*>(&nS[(1+(i))*64 + (kb-32)*4]); \
  az##s = PKF(mk2(v.x,v.y), wz01, az##s); az##s = PKF(mk2(v.z,v.w), wz23, az##s); \
  ar##s = PKF(mk2(v.x,v.y), wr01, ar##s); ar##s = PKF(mk2(v.z,v.w), wr23, ar##s); }
#define OSIG(s,i) zS##s = sigmoidf_(az##s.x + az##s.y); const float rr##s = sigmoidf_(ar##s.x + ar##s.y);
#define OGST(s,i) gS[(1+(i))*64+c] = hc[(1+(i))*64+c] * rr##s;
#define OAMD(s,i) aS##s = mk2(bmOc, 0.f);
#define OM0(s,i) { const float4 v = *reinterpret_cast<const float4*>(&gS[(1+(i))*64 + kb*4]); \
  aS##s = PKF(mk2(v.x,v.y), wm01, aS##s); aS##s = PKF(mk2(v.z,v.w), wm23, aS##s); }
#define OM1(s,i) { aS##s = PKF(aor2##s, um01, aS##s); aS##s = PKF(aor2##s, um23, aS##s); }
#define OM2(s,i) { const float4 v = *reinterpret_cast<const float4*>(&nS[(1+(i))*64 + (kb-32)*4]); \
  aS##s = PKF(mk2(v.x,v.y), wm01, aS##s); aS##s = PKF(mk2(v.z,v.w), wm23, aS##s); }

#define DS0(s,i) { const float4 v = *reinterpret_cast<const float4*>(&hc[(11+(i))*64 + kb*4]); \
  az##s = PKF(mk2(v.x,v.y), wz01, az##s); az##s = PKF(mk2(v.z,v.w), wz23, az##s); \
  ar##s = PKF(mk2(v.x,v.y), wr01, ar##s); ar##s = PKF(mk2(v.z,v.w), wr23, ar##s); }
#define DS1(s,i) { const float4 v = *reinterpret_cast<const float4*>(&nS[(11+(i))*64 + (kb-16)*4]); \
  az##s = PKF(mk2(v.x,v.y), wz01, az##s); az##s = PKF(mk2(v.z,v.w), wz23, az##s); \
  ar##s = PKF(mk2(v.x,v.y), wr01, ar##s); ar##s = PKF(mk2(v.z,v.w), wr23, ar##s); }
#define DSIG(s,i) zS##s = sigmoidf_(az##s.x + az##s.y); const float rr##s = sigmoidf_(ar##s.x + ar##s.y);
#define DGST(s,i) gS[(11+(i))*64+c] = hc[(11+(i))*64+c] * rr##s;
#define DAMD(s,i) aS##s = mk2(bmDc, 0.f);
#define DM0(s,i) { const float4 v = *reinterpret_cast<const float4*>(&gS[(11+(i))*64 + kb*4]); \
  aS##s = PKF(mk2(v.x,v.y), wm01, aS##s); aS##s = PKF(mk2(v.z,v.w), wm23, aS##s); }
#define DM1(s,i) { const float4 v = *reinterpret_cast<const float4*>(&nS[(11+(i))*64 + (kb-16)*4]); \
  aS##s = PKF(mk2(v.x,v.y), wm01, aS##s); aS##s = PKF(mk2(v.z,v.w), wm23, aS##s); }

#define WSPLIT_ZR const f32x2 wz01 = mk2(wz.x, wz.y), wz23 = mk2(wz.z, wz.w), \
                              wr01 = mk2(wr.x, wr.y), wr23 = mk2(wr.z, wr.w);
#define WSPLIT_M  const f32x2 wm01 = mk2(wm.x, wm.y), wm23 = mk2(wm.z, wm.w);

#define OGATE(LIST) { \
  LIST(ZRDECL) LIST(AORD) \
  _Pragma("unroll 2") for (int kb = 0; kb < 16; ++kb) { \
    const float4 wz = pWzO[kb*64+c], wr = pWrO[kb*64+c]; WSPLIT_ZR LIST(OS0) } \
  _Pragma("unroll 2") for (int kb = 16; kb < 32; ++kb) { \
    const float4 wz = pWzO[kb*64+c], wr = pWrO[kb*64+c]; WSPLIT_ZR \
    const float4 h0 = *reinterpret_cast<const float4*>(&hc[(kb-16)*4]); \
    const f32x2 uz01 = mk2(h0.x,h0.y) * wz01, uz23 = mk2(h0.z,h0.w) * wz23; \
    const f32x2 ur01 = mk2(h0.x,h0.y) * wr01, ur23 = mk2(h0.z,h0.w) * wr23; \
    LIST(OS1) } \
  _Pragma("unroll 2") for (int kb = 32; kb < 48; ++kb) { \
    const float4 wz = pWzO[kb*64+c], wr = pWrO[kb*64+c]; WSPLIT_ZR LIST(OS2) } \
  LIST(OSIG) LIST(OGST) LIST(OAMD) \
  _Pragma("unroll 2") for (int kb = 0; kb < 16; ++kb) { \
    const float4 wm = pWmO[kb*64+c]; WSPLIT_M LIST(OM0) } \
  _Pragma("unroll 2") for (int kb = 16; kb < 32; ++kb) { \
    const float4 wm = pWmO[kb*64+c]; WSPLIT_M \
    const float4 h0 = *reinterpret_cast<const float4*>(&hc[(kb-16)*4]); \
    const f32x2 um01 = mk2(h0.x,h0.y) * wm01, um23 = mk2(h0.z,h0.w) * wm23; \
    LIST(OM1) } \
  _Pragma("unroll 2") for (int kb = 32; kb < 48; ++kb) { \
    const float4 wm = pWmO[kb*64+c]; WSPLIT_M LIST(OM2) } }

#define DGATE(LIST) { \
  LIST(ZRDECL) \
  _Pragma("unroll 2") for (int kb = 0; kb < 16; ++kb) { \
    const float4 wz = pWzD[kb*64+c], wr = pWrD[kb*64+c]; WSPLIT_ZR LIST(DS0) } \
  _Pragma("unroll 2") for (int kb = 16; kb < 32; ++kb) { \
    const float4 wz = pWzD[kb*64+c], wr = pWrD[kb*64+c]; WSPLIT_ZR LIST(DS1) } \
  LIST(DSIG) LIST(DGST) LIST(DAMD) \
  _Pragma("unroll 2") for (int kb = 0; kb < 16; ++kb) { \
    const float4 wm = pWmD[kb*64+c]; WSPLIT_M LIST(DM0) } \
  _Pragma("unroll 2") for (int kb = 16; kb < 32; ++kb) { \
    const float4 wm = pWmD[kb*64+c]; WSPLIT_M LIST(DM1) } }

#define OUPD(s,i) { const float h_ = hc[(1+(i))*64+c]; \
  hn[(1+(i))*64+c] = (1.f - zS##s)*h_ + zS##s*tanhf(aS##s.x + aS##s.y); }
#define DUPD(s,i) { const float h_ = hc[(11+(i))*64+c]; \
  hn[(11+(i))*64+c] = (1.f - zS##s)*h_ + zS##s*tanhf(aS##s.x + aS##s.y); }

#define NSO(s,i) nS[(1+(i))*64+c] = \
  sA2[AODB+(i)*11+0]*hd0 + sA2[AODB+(i)*11+1]*hd1 + sA2[AODB+(i)*11+2]*hd2 + sA2[AODB+(i)*11+3]*hd3 \
+ sA2[AODB+(i)*11+4]*hd4 + sA2[AODB+(i)*11+5]*hd5 + sA2[AODB+(i)*11+6]*hd6 + sA2[AODB+(i)*11+7]*hd7 \
+ sA2[AODB+(i)*11+8]*hd8 + sA2[AODB+(i)*11+9]*hd9 + sA2[AODB+(i)*11+10]*hd10;
#define NSD(s,i) nS[(11+(i))*64+c] = \
  sA2[ADOB+(i)*10+0]*ho0 + sA2[ADOB+(i)*10+1]*ho1 + sA2[ADOB+(i)*10+2]*ho2 + sA2[ADOB+(i)*10+3]*ho3 \
+ sA2[ADOB+(i)*10+4]*ho4 + sA2[ADOB+(i)*10+5]*ho5 + sA2[ADOB+(i)*10+6]*ho6 + sA2[ADOB+(i)*10+7]*ho7 \
+ sA2[ADOB+(i)*10+8]*ho8 + sA2[ADOB+(i)*10+9]*ho9;

// 256 threads = 4 waves on ONE batch element; h ping-ponged in LDS (one
// barrier/iter); rows per wave (w0: O 0-4, w1: O 5-9, w2: D 0-5,
// w3: D 6-10 + R); gate matvecs in PACKED fp32 (v_pk_fma_f32, 2 FMA/instr).
__global__ void __launch_bounds__(256) ggnn_main(
    const float* __restrict__ X, const float* __restrict__ A,
    const float* __restrict__ WgR, const float* __restrict__ bgR,
    const float* __restrict__ WgO, const float* __restrict__ bgO,
    const float* __restrict__ WgD, const float* __restrict__ bgD,
    const float* __restrict__ bmR, const float* __restrict__ bmO, const float* __restrict__ bmD,
    const float* __restrict__ W1R, const float* __restrict__ b1R, const float* __restrict__ W2R,
    const float* __restrict__ W1O, const float* __restrict__ b1O, const float* __restrict__ W2O,
    const float* __restrict__ W1D, const float* __restrict__ b1D, const float* __restrict__ W2D,
    const char* __restrict__ ws, const float* __restrict__ tp,
    float* __restrict__ out) {
  const int b = blockIdx.x;
  const int w = threadIdx.x >> 6;
  const int c = threadIdx.x & 63;
  const int tid = threadIdx.x;

  __shared__ __align__(16) float hS0[22 * 64];  // h ping
  __shared__ __align__(16) float hS1[22 * 64];  // h pong
  __shared__ __align__(16) float nS[22 * 64];   // staged n (wave-private rows)
  __shared__ __align__(16) float gS[22 * 64];   // h*r staging; X stage at init
  __shared__ float sA2[ANUM];
  __shared__ float red[16];

  const float4* pk = (const float4*)(ws + 1024);
  const float4* pWzR = pk + 0   * 64;
  const float4* pWrR = pk + 32  * 64;
  const float4* pWmR = pk + 64  * 64;
  const float4* pWzO = pk + 96  * 64;
  const float4* pWrO = pk + 144 * 64;
  const float4* pWmO = pk + 192 * 64;
  const float4* pWzD = pk + 240 * 64;
  const float4* pWrD = pk + 272 * 64;
  const float4* pWmD = pk + 304 * 64;

  const float* Xb = X + (size_t)b * 880;
  const float* Ab = A + (size_t)b * 484;
  for (int t = tid; t < 880; t += 256) gS[t] = Xb[t];
  if (tid < 10) {
    sA2[AROB + tid] = Ab[1 + tid];
    sA2[AORB + tid] = Ab[(1 + tid) * 22];
  }
  for (int t = tid; t < 110; t += 256) {
    const int i = t / 11, j = t - i * 11;
    sA2[AODB + t] = Ab[(1 + i) * 22 + 11 + j];
  }
  for (int t = tid; t < 110; t += 256) {
    const int i = t / 10, j = t - i * 10;
    sA2[ADOB + t] = Ab[(11 + i) * 22 + 1 + j];
  }
  __syncthreads();

  // ---------------- phase 0: h = tanh(Xg @ Wg + bg) -> hS0 ----------------
  {
    float* hw = hS0;
    if (w == 0 || w == 1) {
      float cO = bgO[c];
#pragma unroll 4
      for (int k = 0; k < 40; ++k) cO = fmaf(gS[k], WgO[k * 64 + c], cO);
      float a0 = cO, a1 = cO, a2 = cO, a3 = cO, a4 = cO;
      const int r0 = (w == 0) ? 1 : 6;
#pragma unroll 2
      for (int k = 0; k < 30; ++k) {
        const float wo_ = WgO[(40 + k) * 64 + c];
        a0 = fmaf(gS[(r0 + 0) * 40 + 10 + k], wo_, a0);
        a1 = fmaf(gS[(r0 + 1) * 40 + 10 + k], wo_, a1);
        a2 = fmaf(gS[(r0 + 2) * 40 + 10 + k], wo_, a2);
        a3 = fmaf(gS[(r0 + 3) * 40 + 10 + k], wo_, a3);
        a4 = fmaf(gS[(r0 + 4) * 40 + 10 + k], wo_, a4);
      }
      hw[(r0 + 0) * 64 + c] = tanhf(a0);
      hw[(r0 + 1) * 64 + c] = tanhf(a1);
      hw[(r0 + 2) * 64 + c] = tanhf(a2);
      hw[(r0 + 3) * 64 + c] = tanhf(a3);
      hw[(r0 + 4) * 64 + c] = tanhf(a4);
    } else {
      float cD = bgD[c];
#pragma unroll 4
      for (int k = 0; k < 40; ++k) cD = fmaf(gS[k], WgD[k * 64 + c], cD);
      if (w == 2) {
        float a0 = cD, a1 = cD, a2 = cD, a3 = cD, a4 = cD, a5 = cD;
#pragma unroll 2
        for (int k = 0; k < 30; ++k) {
          const float wd_ = WgD[(40 + k) * 64 + c];
          a0 = fmaf(gS[11 * 40 + 10 + k], wd_, a0);
          a1 = fmaf(gS[12 * 40 + 10 + k], wd_, a1);
          a2 = fmaf(gS[13 * 40 + 10 + k], wd_, a2);
          a3 = fmaf(gS[14 * 40 + 10 + k], wd_, a3);
          a4 = fmaf(gS[15 * 40 + 10 + k], wd_, a4);
          a5 = fmaf(gS[16 * 40 + 10 + k], wd_, a5);
        }
        hw[11 * 64 + c] = tanhf(a0); hw[12 * 64 + c] = tanhf(a1);
        hw[13 * 64 + c] = tanhf(a2); hw[14 * 64 + c] = tanhf(a3);
        hw[15 * 64 + c] = tanhf(a4); hw[16 * 64 + c] = tanhf(a5);
      } else {
        float a0 = cD, a1 = cD, a2 = cD, a3 = cD, a4 = cD;
#pragma unroll 2
        for (int k = 0; k < 30; ++k) {
          const float wd_ = WgD[(40 + k) * 64 + c];
          a0 = fmaf(gS[17 * 40 + 10 + k], wd_, a0);
          a1 = fmaf(gS[18 * 40 + 10 + k], wd_, a1);
          a2 = fmaf(gS[19 * 40 + 10 + k], wd_, a2);
          a3 = fmaf(gS[20 * 40 + 10 + k], wd_, a3);
          a4 = fmaf(gS[21 * 40 + 10 + k], wd_, a4);
        }
        hw[17 * 64 + c] = tanhf(a0); hw[18 * 64 + c] = tanhf(a1);
        hw[19 * 64 + c] = tanhf(a2); hw[20 * 64 + c] = tanhf(a3);
        hw[21 * 64 + c] = tanhf(a4);
        float aR = bgR[c];
#pragma unroll 4
        for (int k = 0; k < 40; ++k) aR = fmaf(gS[k], WgR[k * 64 + c], aR);
        hw[c] = tanhf(aR);
      }
    }
  }
  __syncthreads();

  const float bmOc = bmO[c], bmDc = bmD[c], bmRc = bmR[c];
  float zS0 = 0.f, zS1 = 0.f, zS2 = 0.f, zS3 = 0.f, zS4 = 0.f, zS5 = 0.f;
  f32x2 aS0 = mk2(0.f,0.f), aS1 = mk2(0.f,0.f), aS2 = mk2(0.f,0.f);
  f32x2 aS3 = mk2(0.f,0.f), aS4 = mk2(0.f,0.f), aS5 = mk2(0.f,0.f);

  // ---------------- 3 GRU iterations (ONE barrier each) ----------------
  for (int it = 0; it < 3; ++it) {
    float* hc = (it & 1) ? hS1 : hS0;  // read old h
    float* hn = (it & 1) ? hS0 : hS1;  // write new h

    // (a) stage n (reads OLD hc cross-wave; writes own nS rows)
    if (w == 0 || w == 1) {
      const float hd0 = hc[11*64+c], hd1 = hc[12*64+c], hd2 = hc[13*64+c], hd3 = hc[14*64+c];
      const float hd4 = hc[15*64+c], hd5 = hc[16*64+c], hd6 = hc[17*64+c], hd7 = hc[18*64+c];
      const float hd8 = hc[19*64+c], hd9 = hc[20*64+c], hd10 = hc[21*64+c];
      if (w == 0) { L5A(NSO) } else { L5B(NSO) }
    } else {
      const float ho0 = hc[1*64+c], ho1 = hc[2*64+c], ho2 = hc[3*64+c], ho3 = hc[4*64+c];
      const float ho4 = hc[5*64+c], ho5 = hc[6*64+c], ho6 = hc[7*64+c], ho7 = hc[8*64+c];
      const float ho8 = hc[9*64+c], ho9 = hc[10*64+c];
      if (w == 2) { L6A(NSD) }
      else {
        L5D(NSD)
        nS[c] = sA2[AROB+0]*ho0 + sA2[AROB+1]*ho1 + sA2[AROB+2]*ho2 + sA2[AROB+3]*ho3
              + sA2[AROB+4]*ho4 + sA2[AROB+5]*ho5 + sA2[AROB+6]*ho6 + sA2[AROB+7]*ho7
              + sA2[AROB+8]*ho8 + sA2[AROB+9]*ho9;
      }
    }

    // (b-d) gate matvecs (read OLD hc) + (e) update into hn
    if (w == 0)      { OGATE(L5A) L5A(OUPD) }
    else if (w == 1) { OGATE(L5B) L5B(OUPD) }
    else if (w == 2) { DGATE(L6A) L6A(DUPD) }
    else {
      DGATE(L5D)
      { // gate R -> slot 5
        f32x2 azr = mk2(0.f,0.f), arr = mk2(0.f,0.f);
#pragma unroll 2
        for (int kb = 0; kb < 16; ++kb) {
          const float4 wz = pWzR[kb*64+c], wr = pWrR[kb*64+c]; WSPLIT_ZR
          const float4 v = *reinterpret_cast<const float4*>(&hc[kb*4]);
          azr = PKF(mk2(v.x,v.y), wz01, azr); azr = PKF(mk2(v.z,v.w), wz23, azr);
          arr = PKF(mk2(v.x,v.y), wr01, arr); arr = PKF(mk2(v.z,v.w), wr23, arr);
        }
#pragma unroll 2
        for (int kb = 16; kb < 32; ++kb) {
          const float4 wz = pWzR[kb*64+c], wr = pWrR[kb*64+c]; WSPLIT_ZR
          const float4 v = *reinterpret_cast<const float4*>(&nS[(kb-16)*4]);
          azr = PKF(mk2(v.x,v.y), wz01, azr); azr = PKF(mk2(v.z,v.w), wz23, azr);
          arr = PKF(mk2(v.x,v.y), wr01, arr); arr = PKF(mk2(v.z,v.w), wr23, arr);
        }
        zS5 = sigmoidf_(azr.x + azr.y);
        const float r5 = sigmoidf_(arr.x + arr.y);
        gS[c] = hc[c] * r5;
        aS5 = mk2(bmRc, 0.f);
#pragma unroll 2
        for (int kb = 0; kb < 16; ++kb) {
          const float4 wm = pWmR[kb*64+c]; WSPLIT_M
          const float4 v = *reinterpret_cast<const float4*>(&gS[kb*4]);
          aS5 = PKF(mk2(v.x,v.y), wm01, aS5); aS5 = PKF(mk2(v.z,v.w), wm23, aS5);
        }
#pragma unroll 2
        for (int kb = 16; kb < 32; ++kb) {
          const float4 wm = pWmR[kb*64+c]; WSPLIT_M
          const float4 v = *reinterpret_cast<const float4*>(&nS[(kb-16)*4]);
          aS5 = PKF(mk2(v.x,v.y), wm01, aS5); aS5 = PKF(mk2(v.z,v.w), wm23, aS5);
        }
      }
      L5D(DUPD)
      { const float h_ = hc[c]; hn[c] = (1.f - zS5) * h_ + zS5 * tanhf(aS5.x + aS5.y); }
    }
    __syncthreads();  // single barrier: new-h visible AND hc free for rewrite
  }

  // final h is in hS1 (it=2 wrote hn=hS1)
  float* hF = hS1;

  // ---------------- scores (rows per wave) ----------------
  const int g = c >> 4;
  const int c1 = c & 15;
  float pR = 0.f, pO = 0.f, pD = 0.f;
  int lo, hi;
  if      (w == 0) { lo = 1;  hi = 6;  }
  else if (w == 1) { lo = 6;  hi = 11; }
  else if (w == 2) { lo = 11; hi = 17; }
  else             { lo = 17; hi = 22; }
  for (int rr = lo + g; rr < hi; rr += 4) {
    const float* W1; const float* b1; const float* W2;
    if (rr < 11) { W1 = W1O; b1 = b1O; W2 = W2O; }
    else         { W1 = W1D; b1 = b1D; W2 = W2D; }
    float a = b1[c1];
#pragma unroll 8
    for (int kk = 0; kk < 64; ++kk) {
      const int k = (kk + (g << 4)) & 63;
      a = fmaf(hF[rr * 64 + k], W1[k * 16 + c1], a);
    }
    const float t = tanhf(a) * W2[c1];
    if (rr < 11) pO += t;
    else pD += t;
  }
  if (w == 3 && g == 0) {  // row 0 (R branch)
    float a = b1R[c1];
#pragma unroll 8
    for (int kk = 0; kk < 64; ++kk) {
      a = fmaf(hF[kk], W1R[kk * 16 + c1], a);
    }
    pR = tanhf(a) * W2R[c1];
  }
#pragma unroll
  for (int off = 32; off >= 1; off >>= 1) {
    pR += __shfl_xor(pR, off, 64);
    pO += __shfl_xor(pO, off, 64);
    pD += __shfl_xor(pD, off, 64);
  }
  if (c == 0) { red[w * 4 + 0] = pR; red[w * 4 + 1] = pO; red[w * 4 + 2] = pD; }
  __syncthreads();
  if (w == 0 && c < 60) {
    const float PR = red[0] + red[4] + red[8]  + red[12];
    const float PO = red[1] + red[5] + red[9]  + red[13];
    const float PD = red[2] + red[6] + red[10] + red[14];
    out[(size_t)b * 60 + c] = PR * tp[c] + PO * tp[60 + c] + PD * tp[120 + c];
  }
}

extern "C" void kernel_launch(void* const* d_in, const int* in_sizes, int n_in,
                              void* d_out, int out_size, void* d_ws, size_t ws_size,
                              hipStream_t stream) {
  const float* X   = (const float*)d_in[0];
  const float* A   = (const float*)d_in[1];
  const float* WgR = (const float*)d_in[2];
  const float* bgR = (const float*)d_in[3];
  const float* WgO = (const float*)d_in[4];
  const float* bgO = (const float*)d_in[5];
  const float* WgD = (const float*)d_in[6];
  const float* bgD = (const float*)d_in[7];
  const float* WzR = (const float*)d_in[8];
  const float* WrR = (const float*)d_in[9];
  const float* WmR = (const float*)d_in[10];
  const float* bmR = (const float*)d_in[11];
  const float* WzO = (const float*)d_in[12];
  const float* WrO = (const float*)d_in[13];
  const float* WmO = (const float*)d_in[14];
  const float* bmO = (const float*)d_in[15];
  const float* WzD = (const float*)d_in[16];
  const float* WrD = (const float*)d_in[17];
  const float* WmD = (const float*)d_in[18];
  const float* bmD = (const float*)d_in[19];
  const float* W1R = (const float*)d_in[20];
  const float* b1R = (const float*)d_in[21];
  const float* W2R = (const float*)d_in[22];
  const float* W1O = (const float*)d_in[23];
  const float* b1O = (const float*)d_in[24];
  const float* W2O = (const float*)d_in[25];
  const float* W1D = (const float*)d_in[26];
  const float* b1D = (const float*)d_in[27];
  const float* W2D = (const float*)d_in[28];
  const float* Tmp = (const float*)d_in[29];
  const float* GK  = (const float*)d_in[30];
  const float* GRK = (const float*)d_in[31];
  const float* GB  = (const float*)d_in[32];
  const float* WO  = (const float*)d_in[33];
  const int*   IDX = (const int*)d_in[34];

  float* tp = (float*)d_ws;  // 3*60 floats in the first 1KB
  char*  ws = (char*)d_ws;
  const int B = in_sizes[0] / 880;

  hipLaunchKernelGGL(temporal_kernel, dim3(1), dim3(64), 0, stream, Tmp, GK, GRK, GB, WO, IDX, tp);
  hipLaunchKernelGGL(prep_kernel, dim3(336), dim3(64), 0, stream,
                     WzR, WrR, WmR, WzO, WrO, WmO, WzD, WrD, WmD, ws);
  hipLaunchKernelGGL(ggnn_main, dim3(B), dim3(256), 0, stream,
                     X, A, WgR, bgR, WgO, bgO, WgD, bgD,
                     bmR, bmO, bmD,
                     W1R, b1R, W2R, W1O, b1O, W2O, W1D, b1D, W2D,
                     (const char*)ws, (const float*)tp, (float*)d_out);
}